// Round 10
// baseline (2646.461 us; speedup 1.0000x reference)
//
#include <hip/hip_runtime.h>
#include <hip/hip_bf16.h>

// ---------------------------------------------------------------------------
// Transformer encoder fwd: B=32, S=1024, D=768, L=4, H=1536, C=6
// bf16 MFMA GEMMs. FP16 residual. Output FLOAT32.
// R10: GEMM K-loop gets a 3-deep A-buffer ring (A staged at t+2, like B) so
// A-loads have >= 4 phases (~1us) to cover HBM latency — fixes the tile-
// boundary stall on HBM-streamed A ops (PV reads sc, FFN2 reads h).
// LDS = 3x32K (A ring) + 2x32K (B ping-pong) = 160 KiB. Boundary vmcnt(8).
// Race ledger: bufA[(t+2)%3] last read in tile t-1 (reads done before these
// writes are issued); bufB[t&1] written during t but B-frags are register-
// consumed at tile start. vmcnt(8) at boundary == only the 8 t+2 ops fly.
// ---------------------------------------------------------------------------

typedef float f32x4 __attribute__((ext_vector_type(4)));
typedef unsigned short u16x4 __attribute__((ext_vector_type(4)));
typedef unsigned short u16x8 __attribute__((ext_vector_type(8)));
typedef int   i32x4 __attribute__((ext_vector_type(4)));
typedef __bf16 bf16x8 __attribute__((ext_vector_type(8)));

#define NB  32
#define NS  1024
#define ND  768
#define NH  1536
#define NL  4
#define NM  (NB * NS)   // 32768 rows total

__device__ __forceinline__ unsigned short f2bf(float f) {
    unsigned u = __builtin_bit_cast(unsigned, f);
    unsigned r = (u + 0x7FFFu + ((u >> 16) & 1u)) >> 16;   // RNE
    return (unsigned short)r;
}
__device__ __forceinline__ float bf2f(unsigned short h) {
    return __builtin_bit_cast(float, (unsigned)h << 16);
}
__device__ __forceinline__ unsigned short f2h(float f) {
    _Float16 h = (_Float16)f;
    return __builtin_bit_cast(unsigned short, h);
}
__device__ __forceinline__ float h2f(unsigned short u) {
    _Float16 h = __builtin_bit_cast(_Float16, u);
    return (float)h;
}

__device__ __forceinline__ void gl_lds16(const void* g, void* l) {
    __builtin_amdgcn_global_load_lds(
        (const __attribute__((address_space(1))) unsigned int*)g,
        (__attribute__((address_space(3))) unsigned int*)l, 16, 0, 0);
}

// ---------------- embedding -> fp16 residual --------------------------------
__global__ void embed_kernel(const int* __restrict__ tok,
                             const float* __restrict__ emb,
                             const float* __restrict__ pos,
                             unsigned short* __restrict__ x) {
    const int row = blockIdx.x;
    const int c = threadIdx.x;                 // 192 threads, 4 elems each
    const int tk = tok[row];
    const int s = row & (NS - 1);
    f32x4 e = *(const f32x4*)(emb + (size_t)tk * ND + c * 4);
    f32x4 p = *(const f32x4*)(pos + (size_t)s * ND + c * 4);
    u16x4 o;
    #pragma unroll
    for (int i = 0; i < 4; i++) o[i] = f2h(e[i] + p[i]);
    *(u16x4*)(x + (size_t)row * ND + c * 4) = o;
}

// ---------------- weight fp32 [R][C] -> bf16 transposed [C][R], z-strided ---
__global__ __launch_bounds__(256)
void wt_kernel(const float* __restrict__ in, unsigned short* __restrict__ out,
               int R, int Cc, size_t ozs) {
    __shared__ float ls[64][65];
    const int t = threadIdx.x;
    const size_t zi = (size_t)blockIdx.z * R * Cc;
    const size_t zo = (size_t)blockIdx.z * ozs;
    const int r0 = blockIdx.y * 64, c0 = blockIdx.x * 64;
    #pragma unroll
    for (int i = 0; i < 4; i++) {
        const int r = i * 16 + (t >> 4);
        const int c = (t & 15) * 4;
        f32x4 v = *(const f32x4*)(in + zi + (size_t)(r0 + r) * Cc + c0 + c);
        ls[r][c] = v[0]; ls[r][c + 1] = v[1]; ls[r][c + 2] = v[2]; ls[r][c + 3] = v[3];
    }
    __syncthreads();
    #pragma unroll
    for (int i = 0; i < 2; i++) {
        const int c = i * 32 + (t >> 3);
        const int r = (t & 7) * 8;
        u16x8 o;
        #pragma unroll
        for (int j = 0; j < 8; j++) o[j] = f2bf(ls[r + j][c]);
        *(u16x8*)(out + zo + (size_t)(c0 + c) * R + r0 + r) = o;
    }
}

// ---------------- concat bias [bq|bk] per layer -----------------------------
__global__ void bcat_kernel(const float* __restrict__ bq, const float* __restrict__ bk,
                            float* __restrict__ bqk) {
    const int i = blockIdx.x * 256 + threadIdx.x;       // NL*1536
    const int l = i / NH, j = i % NH;
    bqk[i] = (j < ND) ? bq[l * ND + j] : bk[l * ND + j - ND];
}

// ---------------- LayerNorm fp16 in -> bf16 out, one wave per row -----------
__global__ __launch_bounds__(256)
void ln_kernel(const unsigned short* __restrict__ x, const float* __restrict__ g,
               const float* __restrict__ bta, unsigned short* __restrict__ out) {
    const int row = blockIdx.x * 4 + (threadIdx.x >> 6);
    const int l = threadIdx.x & 63;
    const unsigned short* xr = x + (size_t)row * ND;
    f32x4 vv[3];
    float s = 0.f, ss = 0.f;
    #pragma unroll
    for (int j = 0; j < 3; j++) {
        u16x4 hv = *(const u16x4*)(xr + (j * 64 + l) * 4);
        #pragma unroll
        for (int i = 0; i < 4; i++) {
            vv[j][i] = h2f(hv[i]);
            s += vv[j][i]; ss += vv[j][i] * vv[j][i];
        }
    }
    #pragma unroll
    for (int off = 32; off >= 1; off >>= 1) {
        s += __shfl_xor(s, off); ss += __shfl_xor(ss, off);
    }
    const float mean = s * (1.0f / ND);
    const float var = ss * (1.0f / ND) - mean * mean;
    const float rstd = rsqrtf(var + 1e-5f);
    #pragma unroll
    for (int j = 0; j < 3; j++) {
        const int c = (j * 64 + l) * 4;
        f32x4 gv = *(const f32x4*)(g + c);
        f32x4 bv = *(const f32x4*)(bta + c);
        u16x4 o;
        #pragma unroll
        for (int i = 0; i < 4; i++) o[i] = f2bf((vv[j][i] - mean) * rstd * gv[i] + bv[i]);
        *(u16x4*)(out + (size_t)row * ND + c) = o;
    }
}

// ---------------- GEMM 256x256, 8-phase, 3-deep-A: C = A[M,K] @ Bt[N,K]^T ---
// 512 threads = 8 waves (2M x 4N), per-wave 128x64 out, BK=64.
// LDS 160 KiB: A ring x3 (0,32K,64K) + B ping-pong (96K,128K).
// Tile t stages A(t+2) at p0/p1 and B(t+2) at p2/p3; boundary vmcnt(8).
// T2 both-sides XOR swizzle; setprio around MFMA; raw s_barrier only.
// Epilogue: LDS bounce; quarter-wave conflict-free write+read, coalesced st.
// EPI: 0 = scale+bias -> bf16; 1 = relu(bias+v) -> bf16; 2 = FP16 C += v
// BROW: bias indexed by output ROW m (for the V^T-producing GEMM).
template<int EPI, int BROW>
__global__ __launch_bounds__(512, 2)
void gemm256_kernel(const unsigned short* __restrict__ A,
                    const unsigned short* __restrict__ Bt,
                    const float* __restrict__ bias,
                    void* __restrict__ Cv,
                    int N, int K, int lda, int ldb,
                    long sA, long sB, long sC, float scale, int doswz) {
    __shared__ __align__(16) unsigned char lds[163840];   // 160 KiB
    const int tid = threadIdx.x;
    const int wid = tid >> 6, l = tid & 63;
    const int wr = wid >> 2, wc = wid & 3;     // wave -> 2x4 grid
    const int fr = l & 15, fq = l >> 4;

    int bn = blockIdx.x, bm = blockIdx.y, bz = blockIdx.z;
    if (doswz) {                               // T1: XCD remap over full grid
        const int gx = gridDim.x, gy = gridDim.y;
        const int nwg = gx * gy * gridDim.z;
        const int flat = (bz * gy + bm) * gx + bn;
        int s = (flat & 7) * (nwg >> 3) + (flat >> 3);
        bn = s % gx; s /= gx; bm = s % gy; bz = s / gy;
    }

    const unsigned short* Ab = A + (size_t)bz * sA + (size_t)(bm * 256) * lda;
    const unsigned short* Bb = Bt + (size_t)bz * sB + (size_t)(bn * 256) * ldb;

    // staging: thread covers row (tid>>3), 8 elems; source col pre-swizzled
    // so the LINEAR gl_lds write lands swizzled data (both-sides T2).
    const int srow = tid >> 3;                           // 0..63
    const int scol = ((tid & 7) ^ (srow & 7)) * 8;       // elems
    const unsigned ldst = (unsigned)wid * 1024u;         // wave base (bytes)

    auto stageA = [&](unsigned bbase, int kt, int h) {
        #pragma unroll
        for (int li = 0; li < 2; li++)
            gl_lds16(Ab + (size_t)(h * 128 + li * 64 + srow) * lda + (kt * 64 + scol),
                     lds + bbase + (unsigned)h * 16384u + (unsigned)li * 8192u + ldst);
    };
    auto stageB = [&](unsigned bbase, int kt, int h) {
        #pragma unroll
        for (int li = 0; li < 2; li++)
            gl_lds16(Bb + (size_t)(h * 128 + li * 64 + srow) * ldb + (kt * 64 + scol),
                     lds + bbase + (unsigned)h * 16384u + (unsigned)li * 8192u + ldst);
    };
    auto ldaf = [&](unsigned bbase, int mi, int kk) -> bf16x8 {
        const unsigned r = (unsigned)(mi * 16 + fr);
        unsigned byt = r * 128u + (unsigned)kk * 64u + (unsigned)fq * 16u;
        byt ^= (r & 7u) << 4;
        return *(const bf16x8*)(lds + bbase + (unsigned)wr * 16384u + byt);
    };
    auto ldbf = [&](unsigned bbase, int ni, int kk) -> bf16x8 {
        const unsigned r = (unsigned)((wc & 1) * 64 + ni * 16 + fr);
        unsigned byt = r * 128u + (unsigned)kk * 64u + (unsigned)fq * 16u;
        byt ^= (r & 7u) << 4;
        return *(const bf16x8*)(lds + bbase + (unsigned)(wc >> 1) * 16384u + byt);
    };

    const int NT = K >> 6;                     // >= 12 for all our shapes
    f32x4 acc[8][4] = {};

    // ---- prologue: B0,A0 (first 8 ops) then B1,A1; wait for B0+A0 ---------
    stageB(98304u, 0, 0);          stageB(98304u, 0, 1);
    stageA(0u, 0, 0);              stageA(0u, 0, 1);
    stageB(98304u + 32768u, 1, 0); stageB(98304u + 32768u, 1, 1);
    stageA(32768u, 1, 0);          stageA(32768u, 1, 1);
    asm volatile("s_waitcnt vmcnt(8)" ::: "memory");
    __builtin_amdgcn_s_barrier();
    __builtin_amdgcn_sched_barrier(0);

    int aRd = 0, aWr = 2;                      // A ring indices: t%3, (t+2)%3
    for (int t = 0; t < NT; ++t) {
        const unsigned baseA = (unsigned)aRd * 32768u;
        const unsigned baseB = 98304u + (unsigned)(t & 1) * 32768u;
        const unsigned stgA  = (unsigned)aWr * 32768u;
        const unsigned stgB  = baseB;          // (t+2)&1 == t&1

        bf16x8 bfr[8];                         // B-frags, live all 4 phases
        #pragma unroll
        for (int ni = 0; ni < 4; ni++) {
            bfr[ni * 2 + 0] = ldbf(baseB, ni, 0);
            bfr[ni * 2 + 1] = ldbf(baseB, ni, 1);
        }
        #pragma unroll
        for (int p = 0; p < 4; p++) {
            bf16x8 a0 = ldaf(baseA, 2 * p,     0);
            bf16x8 a1 = ldaf(baseA, 2 * p,     1);
            bf16x8 a2 = ldaf(baseA, 2 * p + 1, 0);
            bf16x8 a3 = ldaf(baseA, 2 * p + 1, 1);
            if (p < 2) { if (t + 2 < NT) stageA(stgA, t + 2, p); }
            else       { if (t + 2 < NT) stageB(stgB, t + 2, p - 2); }
            if (p == 3) {                      // boundary: 8 newest (t+2) fly
                if (t + 2 < NT) asm volatile("s_waitcnt vmcnt(8)" ::: "memory");
                else            asm volatile("s_waitcnt vmcnt(0)" ::: "memory");
            }
            __builtin_amdgcn_s_barrier();
            asm volatile("s_waitcnt lgkmcnt(0)" ::: "memory");
            __builtin_amdgcn_sched_barrier(0);
            __builtin_amdgcn_s_setprio(1);
            #pragma unroll
            for (int ni = 0; ni < 4; ni++) {
                acc[2 * p][ni] = __builtin_amdgcn_mfma_f32_16x16x32_bf16(
                    a0, bfr[ni * 2 + 0], acc[2 * p][ni], 0, 0, 0);
                acc[2 * p][ni] = __builtin_amdgcn_mfma_f32_16x16x32_bf16(
                    a1, bfr[ni * 2 + 1], acc[2 * p][ni], 0, 0, 0);
                acc[2 * p + 1][ni] = __builtin_amdgcn_mfma_f32_16x16x32_bf16(
                    a2, bfr[ni * 2 + 0], acc[2 * p + 1][ni], 0, 0, 0);
                acc[2 * p + 1][ni] = __builtin_amdgcn_mfma_f32_16x16x32_bf16(
                    a3, bfr[ni * 2 + 1], acc[2 * p + 1][ni], 0, 0, 0);
            }
            __builtin_amdgcn_s_setprio(0);
            __builtin_amdgcn_sched_barrier(0);
            __builtin_amdgcn_s_barrier();
            __builtin_amdgcn_sched_barrier(0);
        }
        aRd = (aRd == 2) ? 0 : aRd + 1;
        aWr = (aWr == 2) ? 0 : aWr + 1;
    }

    // ---- epilogue: LDS-bounce, conflict-free read, coalesced stores --------
    const int erow = tid >> 4;                  // 0..31 (fixed per quarter-wave)
    const int echk = tid & 15;                  // 16B-chunk base within row
    #pragma unroll
    for (int h2 = 0; h2 < 2; ++h2) {
        __builtin_amdgcn_s_barrier();           // K-loop done / prev pass read
        if (wr == h2) {                         // this half's acc -> LDS fp32
            #pragma unroll
            for (int mi = 0; mi < 8; mi++) {
                #pragma unroll
                for (int ni = 0; ni < 4; ni++) {
                    const int nl = wc * 64 + ni * 16 + fr;      // block-local col
                    const float bcol = (!BROW && bias) ? bias[bn * 256 + nl] : 0.0f;
                    f32x4 brow = {0, 0, 0, 0};
                    if (BROW) brow = *(const f32x4*)(bias + bm * 256 + h2 * 128 + mi * 16 + fq * 4);
                    #pragma unroll
                    for (int r = 0; r < 4; r++) {
                        const int lm = mi * 16 + fq * 4 + r;    // 0..127
                        float v = acc[mi][ni][r] * scale + (BROW ? brow[r] : bcol);
                        if (EPI == 1) v = fmaxf(v, 0.0f);
                        const unsigned byt = ((unsigned)lm * 1024u + (unsigned)nl * 4u)
                                             ^ ((unsigned)(lm & 7) << 4);
                        *(float*)(lds + byt) = v;
                    }
                }
            }
        }
        __builtin_amdgcn_s_barrier();
        #pragma unroll
        for (int j = 0; j < 16; j++) {
            const int row = erow + 32 * (j >> 2);               // 0..127
            const int c   = echk + 16 * (j & 3);                // 0..63 chunks
            const unsigned byt = ((unsigned)row * 1024u + (unsigned)c * 16u)
                                 ^ ((unsigned)(row & 7) << 4);
            f32x4 v = *(const f32x4*)(lds + byt);
            const int m = bm * 256 + h2 * 128 + row;
            const int ncol = bn * 256 + c * 4;
            const size_t offc = (size_t)bz * sC + (size_t)m * N + ncol;
            if (EPI == 2) {                     // fp16 residual RMW
                unsigned short* cp = (unsigned short*)Cv + offc;
                u16x4 hv = *(const u16x4*)cp;
                u16x4 o;
                #pragma unroll
                for (int r = 0; r < 4; r++) o[r] = f2h(h2f(hv[r]) + v[r]);
                *(u16x4*)cp = o;
            } else {
                u16x4 o;
                o[0] = f2bf(v[0]); o[1] = f2bf(v[1]); o[2] = f2bf(v[2]); o[3] = f2bf(v[3]);
                *(u16x4*)((unsigned short*)Cv + offc) = o;
            }
        }
    }
}

// ---------------- masked softmax (mask from tokens), group-local ------------
__global__ __launch_bounds__(256)
void softmax_kernel(unsigned short* __restrict__ sc, const int* __restrict__ tokg) {
    const int row = blockIdx.x * 4 + (threadIdx.x >> 6);   // row in [0, G*NS)
    const int l = threadIdx.x & 63;
    const int b = row >> 10;                               // batch local to group
    unsigned short* rp = sc + (size_t)row * NS;
    const int* trow = tokg + (size_t)b * NS;
    float v[16];
    float mx = -3.4e38f;
    #pragma unroll
    for (int j = 0; j < 2; j++) {
        u16x8 u = *(const u16x8*)(rp + j * 512 + l * 8);
        i32x4 t0 = *(const i32x4*)(trow + j * 512 + l * 8);
        i32x4 t1 = *(const i32x4*)(trow + j * 512 + l * 8 + 4);
        #pragma unroll
        for (int i = 0; i < 8; i++) {
            const int tk = (i < 4) ? t0[i] : t1[i - 4];
            const float s = (tk == 0) ? -__builtin_inff() : bf2f(u[i]);
            v[j * 8 + i] = s;
            mx = fmaxf(mx, s);
        }
    }
    #pragma unroll
    for (int off = 32; off >= 1; off >>= 1) mx = fmaxf(mx, __shfl_xor(mx, off));
    float sum = 0.f;
    #pragma unroll
    for (int i = 0; i < 16; i++) { v[i] = __expf(v[i] - mx); sum += v[i]; }
    #pragma unroll
    for (int off = 32; off >= 1; off >>= 1) sum += __shfl_xor(sum, off);
    const float inv = 1.0f / sum;
    #pragma unroll
    for (int j = 0; j < 2; j++) {
        u16x8 o;
        #pragma unroll
        for (int i = 0; i < 8; i++) o[i] = f2bf(v[j * 8 + i] * inv);
        *(u16x8*)(rp + j * 512 + l * 8) = o;
    }
}

// ---------------- pool stage 1: partial masked sums over 128-row chunks -----
__global__ __launch_bounds__(256)
void pool1_kernel(const unsigned short* __restrict__ ln,
                  const int* __restrict__ tokg,
                  float* __restrict__ part, float* __restrict__ cnts,
                  int gbase) {                     // gbase: global batch offset
    const int d = blockIdx.x * 256 + threadIdx.x;  // 0..767
    const int b = blockIdx.y;                      // local batch
    const int z = blockIdx.z;                      // seq chunk 0..7
    float s = 0.f, cnt = 0.f;
    const int i0 = z * 128;
    for (int i = i0; i < i0 + 128; i++) {
        const int tk = tokg[b * NS + i];
        if (tk != 0) { s += bf2f(ln[((size_t)b * NS + i) * ND + d]); cnt += 1.0f; }
    }
    part[((size_t)z * NB + (gbase + b)) * ND + d] = s;
    if (d == 0) cnts[z * NB + (gbase + b)] = cnt;
}

// ---------------- pool stage 2: finalize -----------------------------------
__global__ __launch_bounds__(256)
void pool2_kernel(const float* __restrict__ part, const float* __restrict__ cnts,
                  float* __restrict__ pooled) {
    const int d = blockIdx.x * 256 + threadIdx.x;
    const int b = blockIdx.y;                      // global batch
    float s = 0.f, cnt = 0.f;
    #pragma unroll
    for (int z = 0; z < 8; z++) {
        s += part[((size_t)z * NB + b) * ND + d];
        cnt += cnts[z * NB + b];
    }
    pooled[(size_t)b * ND + d] = s / fmaxf(cnt, 1.0f);
}

// ---------------- classifier -> FLOAT32 output ------------------------------
__global__ void cls_kernel(const float* __restrict__ pooled, const float* __restrict__ wc,
                           const float* __restrict__ bc, float* __restrict__ out) {
    const int b = blockIdx.x;
    const int l = threadIdx.x;                  // 64 threads
    float a[6] = {0, 0, 0, 0, 0, 0};
    for (int d = l; d < ND; d += 64) {
        const float p = pooled[b * ND + d];
        #pragma unroll
        for (int c = 0; c < 6; c++) a[c] += p * wc[d * 6 + c];
    }
    #pragma unroll
    for (int c = 0; c < 6; c++) {
        #pragma unroll
        for (int off = 32; off >= 1; off >>= 1) a[c] += __shfl_xor(a[c], off);
    }
    if (l == 0) {
        #pragma unroll
        for (int c = 0; c < 6; c++) out[b * 6 + c] = a[c] + bc[c];
    }
}

__global__ void zero_out_kernel(float* out, int nel) {
    const int i = blockIdx.x * 256 + threadIdx.x;
    if (i < nel) out[i] = 0.0f;
}

// ---------------------------------------------------------------------------
extern "C" void kernel_launch(void* const* d_in, const int* in_sizes, int n_in,
                              void* d_out, int out_size, void* d_ws, size_t ws_size,
                              hipStream_t stream) {
    const int*   tok  = (const int*)d_in[0];
    const float* emb  = (const float*)d_in[1];
    const float* pos  = (const float*)d_in[2];
    const float* ln1w = (const float*)d_in[3];
    const float* ln1b = (const float*)d_in[4];
    const float* ln2w = (const float*)d_in[5];
    const float* ln2b = (const float*)d_in[6];
    const float* wq   = (const float*)d_in[7];
    const float* bq   = (const float*)d_in[8];
    const float* wk   = (const float*)d_in[9];
    const float* bk   = (const float*)d_in[10];
    const float* wv   = (const float*)d_in[11];
    const float* bv   = (const float*)d_in[12];
    const float* w1   = (const float*)d_in[13];
    const float* b1   = (const float*)d_in[14];
    const float* w2   = (const float*)d_in[15];
    const float* b2   = (const float*)d_in[16];
    const float* lnfw = (const float*)d_in[17];
    const float* lnfb = (const float*)d_in[18];
    const float* wcw  = (const float*)d_in[19];
    const float* bcb  = (const float*)d_in[20];
    float* out = (float*)d_out;                 // FLOAT32 output (ref dtype)

    // ---- fixed workspace carve-up ----
    size_t off = 0;
    auto carve = [&](size_t bytes) -> char* {
        char* p = (char*)d_ws + off;
        off += (bytes + 255) & ~(size_t)255;
        return p;
    };
    unsigned short* x = (unsigned short*)carve((size_t)NM * ND * 2);   // fp16 residual
    unsigned short* wqkT = (unsigned short*)carve((size_t)NL * NH * ND * 2); // [l][1536][768]
    unsigned short* wvT  = (unsigned short*)carve((size_t)NL * ND * ND * 2);
    unsigned short* w1T  = (unsigned short*)carve((size_t)NL * ND * NH * 2);
    unsigned short* w2T  = (unsigned short*)carve((size_t)NL * NH * ND * 2);
    float* bqk    = (float*)carve((size_t)NL * NH * 4);
    float* part   = (float*)carve((size_t)8 * NB * ND * 4);
    float* cnts   = (float*)carve((size_t)8 * NB * 4);
    float* pooled = (float*)carve((size_t)NB * ND * 4);

    // ---- adaptive group size ----
    int G = 32;
    while (G >= 1) {
        const size_t pool = (size_t)G *
            ((size_t)NS * ND * 2      // n
           + (size_t)NS * NH * 2      // qk (aliased by h)
           + (size_t)NS * ND * 2      // vt
           + (size_t)NS * NS * 2);    // sc
        if (off + pool <= ws_size) break;
        G >>= 1;
    }
    if (G < 1) {
        zero_out_kernel<<<(out_size + 255) / 256, 256, 0, stream>>>(out, out_size);
        return;
    }
    const int MG = G * NS;                       // rows per group
    unsigned short* n  = (unsigned short*)carve((size_t)MG * ND * 2);
    unsigned short* qk = (unsigned short*)carve((size_t)MG * NH * 2);
    unsigned short* vt = (unsigned short*)carve((size_t)MG * ND * 2); // [b][768][1024]
    unsigned short* sc = (unsigned short*)carve((size_t)G * NS * NS * 2);
    unsigned short* h  = qk;                     // alias: qk dead after scores

    // ---- prepass ----
    embed_kernel<<<NM, 192, 0, stream>>>(tok, emb, pos, x);
    wt_kernel<<<dim3(12, 12, NL), 256, 0, stream>>>(wq, wqkT,            ND, ND, (size_t)NH * ND);
    wt_kernel<<<dim3(12, 12, NL), 256, 0, stream>>>(wk, wqkT + ND * ND,  ND, ND, (size_t)NH * ND);
    wt_kernel<<<dim3(12, 12, NL), 256, 0, stream>>>(wv, wvT,             ND, ND, (size_t)ND * ND);
    wt_kernel<<<dim3(24, 12, NL), 256, 0, stream>>>(w1, w1T,             ND, NH, (size_t)ND * NH);
    wt_kernel<<<dim3(12, 24, NL), 256, 0, stream>>>(w2, w2T,             NH, ND, (size_t)NH * ND);
    bcat_kernel<<<NL * NH / 256, 256, 0, stream>>>(bq, bk, bqk);

    const float iscale = 1.0f / sqrtf((float)ND);
    const int NGroups = NB / G;
    const int MT = MG / 256;                     // row tiles of the big GEMMs (=4G)
    // all grids here have nwg % 8 == 0 -> T1 swizzle everywhere
    for (int l = 0; l < NL; l++) {
        for (int g = 0; g < NGroups; g++) {
            const size_t rowoff = (size_t)g * MG;
            unsigned short* xg = x + rowoff * ND;
            ln_kernel<<<MG / 4, 256, 0, stream>>>(xg, ln1w + l * ND, ln1b + l * ND, n);
            // QK fused: qk[MG][1536] = n @ [wq|wk]^T + [bq|bk]
            gemm256_kernel<0, 0><<<dim3(6, MT, 1), 512, 0, stream>>>(
                n, wqkT + (size_t)l * NH * ND, bqk + l * NH, qk,
                NH, ND, ND, ND, 0, 0, 0, 1.0f, ((6 * MT) % 8 == 0) ? 1 : 0);
            // V^T direct: vt[b][d][s] = wvT[d][:] . n[b][s][:] + bv[d]
            gemm256_kernel<0, 1><<<dim3(4, 3, G), 512, 0, stream>>>(
                wvT + (size_t)l * ND * ND, n, bv + l * ND, vt,
                NS, ND, ND, ND, 0, (long)NS * ND, (long)ND * NS, 1.0f,
                ((12 * G) % 8 == 0) ? 1 : 0);
            // scores = q @ k^T * iscale   (q,k strided views of qk)
            gemm256_kernel<0, 0><<<dim3(4, 4, G), 512, 0, stream>>>(
                qk, qk + ND, nullptr, sc,
                NS, ND, NH, NH, (long)NS * NH, (long)NS * NH, (long)NS * NS, iscale,
                ((16 * G) % 8 == 0) ? 1 : 0);
            softmax_kernel<<<MG / 4, 256, 0, stream>>>(sc, tok + rowoff);
            // x += attn @ V   (Bt = vt)
            gemm256_kernel<2, 0><<<dim3(3, 4, G), 512, 0, stream>>>(
                sc, vt, nullptr, xg,
                ND, NS, NS, NS, (long)NS * NS, (long)ND * NS, (long)NS * ND, 1.0f,
                ((12 * G) % 8 == 0) ? 1 : 0);
            ln_kernel<<<MG / 4, 256, 0, stream>>>(xg, ln2w + l * ND, ln2b + l * ND, n);
            gemm256_kernel<1, 0><<<dim3(6, MT, 1), 512, 0, stream>>>(
                n, w1T + (size_t)l * ND * NH, b1 + l * NH, h,
                NH, ND, ND, ND, 0, 0, 0, 1.0f, ((6 * MT) % 8 == 0) ? 1 : 0);
            gemm256_kernel<2, 0><<<dim3(3, MT, 1), 512, 0, stream>>>(
                h, w2T + (size_t)l * ND * NH, b2 + l * ND, xg,
                ND, NH, NH, NH, 0, 0, 0, 1.0f, ((3 * MT) % 8 == 0) ? 1 : 0);
        }
    }
    for (int g = 0; g < NGroups; g++) {
        const size_t rowoff = (size_t)g * MG;
        ln_kernel<<<MG / 4, 256, 0, stream>>>(x + rowoff * ND, lnfw, lnfb, n);
        pool1_kernel<<<dim3(3, G, 8), 256, 0, stream>>>(n, tok + rowoff, part, cnts, g * G);
    }
    pool2_kernel<<<dim3(3, NB), 256, 0, stream>>>(part, cnts, pooled);
    cls_kernel<<<NB, 64, 0, stream>>>(pooled, wcw, bcb, out);
}

// Round 11
// 2495.662 us; speedup vs baseline: 1.0604x; 1.0604x over previous
//
#include <hip/hip_runtime.h>
#include <hip/hip_bf16.h>

// ---------------------------------------------------------------------------
// Transformer encoder fwd: B=32, S=1024, D=768, L=4, H=1536, C=6
// bf16 MFMA GEMMs. FP16 residual. Output FLOAT32.
// R11 = R9 base (A staged t+1, B staged t+2, vmcnt(4), 128 KiB LDS) with the
// post-MFMA barrier removed for phases 0-2 (kept at the tile boundary).
// Race ledger: in-tile ds_reads hit stable buffers; stageB(t+2) writes the
// buffer whose B-frags were register-loaded at tile start, and a wave reaches
// p2 only after the p1 barrier => every wave is past p0's lgkmcnt(0) => bfr
// reads complete. Cross-tile visibility: boundary vmcnt(4)+barrier unchanged.
// ---------------------------------------------------------------------------

typedef float f32x4 __attribute__((ext_vector_type(4)));
typedef unsigned short u16x4 __attribute__((ext_vector_type(4)));
typedef unsigned short u16x8 __attribute__((ext_vector_type(8)));
typedef int   i32x4 __attribute__((ext_vector_type(4)));
typedef __bf16 bf16x8 __attribute__((ext_vector_type(8)));

#define NB  32
#define NS  1024
#define ND  768
#define NH  1536
#define NL  4
#define NM  (NB * NS)   // 32768 rows total

__device__ __forceinline__ unsigned short f2bf(float f) {
    unsigned u = __builtin_bit_cast(unsigned, f);
    unsigned r = (u + 0x7FFFu + ((u >> 16) & 1u)) >> 16;   // RNE
    return (unsigned short)r;
}
__device__ __forceinline__ float bf2f(unsigned short h) {
    return __builtin_bit_cast(float, (unsigned)h << 16);
}
__device__ __forceinline__ unsigned short f2h(float f) {
    _Float16 h = (_Float16)f;
    return __builtin_bit_cast(unsigned short, h);
}
__device__ __forceinline__ float h2f(unsigned short u) {
    _Float16 h = __builtin_bit_cast(_Float16, u);
    return (float)h;
}

__device__ __forceinline__ void gl_lds16(const void* g, void* l) {
    __builtin_amdgcn_global_load_lds(
        (const __attribute__((address_space(1))) unsigned int*)g,
        (__attribute__((address_space(3))) unsigned int*)l, 16, 0, 0);
}

// ---------------- embedding -> fp16 residual --------------------------------
__global__ void embed_kernel(const int* __restrict__ tok,
                             const float* __restrict__ emb,
                             const float* __restrict__ pos,
                             unsigned short* __restrict__ x) {
    const int row = blockIdx.x;
    const int c = threadIdx.x;                 // 192 threads, 4 elems each
    const int tk = tok[row];
    const int s = row & (NS - 1);
    f32x4 e = *(const f32x4*)(emb + (size_t)tk * ND + c * 4);
    f32x4 p = *(const f32x4*)(pos + (size_t)s * ND + c * 4);
    u16x4 o;
    #pragma unroll
    for (int i = 0; i < 4; i++) o[i] = f2h(e[i] + p[i]);
    *(u16x4*)(x + (size_t)row * ND + c * 4) = o;
}

// ---------------- weight fp32 [R][C] -> bf16 transposed [C][R], z-strided ---
__global__ __launch_bounds__(256)
void wt_kernel(const float* __restrict__ in, unsigned short* __restrict__ out,
               int R, int Cc, size_t ozs) {
    __shared__ float ls[64][65];
    const int t = threadIdx.x;
    const size_t zi = (size_t)blockIdx.z * R * Cc;
    const size_t zo = (size_t)blockIdx.z * ozs;
    const int r0 = blockIdx.y * 64, c0 = blockIdx.x * 64;
    #pragma unroll
    for (int i = 0; i < 4; i++) {
        const int r = i * 16 + (t >> 4);
        const int c = (t & 15) * 4;
        f32x4 v = *(const f32x4*)(in + zi + (size_t)(r0 + r) * Cc + c0 + c);
        ls[r][c] = v[0]; ls[r][c + 1] = v[1]; ls[r][c + 2] = v[2]; ls[r][c + 3] = v[3];
    }
    __syncthreads();
    #pragma unroll
    for (int i = 0; i < 2; i++) {
        const int c = i * 32 + (t >> 3);
        const int r = (t & 7) * 8;
        u16x8 o;
        #pragma unroll
        for (int j = 0; j < 8; j++) o[j] = f2bf(ls[r + j][c]);
        *(u16x8*)(out + zo + (size_t)(c0 + c) * R + r0 + r) = o;
    }
}

// ---------------- concat bias [bq|bk] per layer -----------------------------
__global__ void bcat_kernel(const float* __restrict__ bq, const float* __restrict__ bk,
                            float* __restrict__ bqk) {
    const int i = blockIdx.x * 256 + threadIdx.x;       // NL*1536
    const int l = i / NH, j = i % NH;
    bqk[i] = (j < ND) ? bq[l * ND + j] : bk[l * ND + j - ND];
}

// ---------------- LayerNorm fp16 in -> bf16 out, one wave per row -----------
__global__ __launch_bounds__(256)
void ln_kernel(const unsigned short* __restrict__ x, const float* __restrict__ g,
               const float* __restrict__ bta, unsigned short* __restrict__ out) {
    const int row = blockIdx.x * 4 + (threadIdx.x >> 6);
    const int l = threadIdx.x & 63;
    const unsigned short* xr = x + (size_t)row * ND;
    f32x4 vv[3];
    float s = 0.f, ss = 0.f;
    #pragma unroll
    for (int j = 0; j < 3; j++) {
        u16x4 hv = *(const u16x4*)(xr + (j * 64 + l) * 4);
        #pragma unroll
        for (int i = 0; i < 4; i++) {
            vv[j][i] = h2f(hv[i]);
            s += vv[j][i]; ss += vv[j][i] * vv[j][i];
        }
    }
    #pragma unroll
    for (int off = 32; off >= 1; off >>= 1) {
        s += __shfl_xor(s, off); ss += __shfl_xor(ss, off);
    }
    const float mean = s * (1.0f / ND);
    const float var = ss * (1.0f / ND) - mean * mean;
    const float rstd = rsqrtf(var + 1e-5f);
    #pragma unroll
    for (int j = 0; j < 3; j++) {
        const int c = (j * 64 + l) * 4;
        f32x4 gv = *(const f32x4*)(g + c);
        f32x4 bv = *(const f32x4*)(bta + c);
        u16x4 o;
        #pragma unroll
        for (int i = 0; i < 4; i++) o[i] = f2bf((vv[j][i] - mean) * rstd * gv[i] + bv[i]);
        *(u16x4*)(out + (size_t)row * ND + c) = o;
    }
}

// ---------------- GEMM 256x256, 8-phase: C = A[M,K] @ Bt[N,K]^T -------------
// 512 threads = 8 waves (2M x 4N), per-wave 128x64 out, BK=64, dbuf LDS 128K.
// K-loop: T2 both-sides XOR swizzle, counted vmcnt(4), setprio around MFMA.
// Per-phase: pre-MFMA barrier only; post-MFMA barrier at tile boundary only.
// Epilogue: LDS bounce; quarter-wave conflict-free write+read, coalesced st.
// EPI: 0 = scale+bias -> bf16; 1 = relu(bias+v) -> bf16; 2 = FP16 C += v
// BROW: bias indexed by output ROW m (for the V^T-producing GEMM).
template<int EPI, int BROW>
__global__ __launch_bounds__(512, 2)
void gemm256_kernel(const unsigned short* __restrict__ A,
                    const unsigned short* __restrict__ Bt,
                    const float* __restrict__ bias,
                    void* __restrict__ Cv,
                    int N, int K, int lda, int ldb,
                    long sA, long sB, long sC, float scale, int doswz) {
    __shared__ unsigned short lds[65536];      // 128 KiB
    const int tid = threadIdx.x;
    const int wid = tid >> 6, l = tid & 63;
    const int wr = wid >> 2, wc = wid & 3;     // wave -> 2x4 grid
    const int fr = l & 15, fq = l >> 4;

    int bn = blockIdx.x, bm = blockIdx.y, bz = blockIdx.z;
    if (doswz) {                               // T1: XCD remap over full grid
        const int gx = gridDim.x, gy = gridDim.y;
        const int nwg = gx * gy * gridDim.z;
        const int flat = (bz * gy + bm) * gx + bn;
        int s = (flat & 7) * (nwg >> 3) + (flat >> 3);
        bn = s % gx; s /= gx; bm = s % gy; bz = s / gy;
    }

    const unsigned short* Ab = A + (size_t)bz * sA + (size_t)(bm * 256) * lda;
    const unsigned short* Bb = Bt + (size_t)bz * sB + (size_t)(bn * 256) * ldb;

    // staging: thread covers row (tid>>3), 8 elems; source col pre-swizzled
    // so the LINEAR gl_lds write lands swizzled data (both-sides T2).
    const int srow = tid >> 3;                           // 0..63
    const int scol = ((tid & 7) ^ (srow & 7)) * 8;       // elems
    const unsigned ldst = (unsigned)wid * 1024u;         // wave base (bytes)

    auto stageA = [&](int kt, int h) {
        const unsigned base = (unsigned)(kt & 1) * 65536u + (unsigned)h * 16384u;
        #pragma unroll
        for (int li = 0; li < 2; li++)
            gl_lds16(Ab + (size_t)(h * 128 + li * 64 + srow) * lda + (kt * 64 + scol),
                     (char*)lds + base + (unsigned)li * 8192u + ldst);
    };
    auto stageB = [&](int kt, int h) {
        const unsigned base = (unsigned)(kt & 1) * 65536u + 32768u + (unsigned)h * 16384u;
        #pragma unroll
        for (int li = 0; li < 2; li++)
            gl_lds16(Bb + (size_t)(h * 128 + li * 64 + srow) * ldb + (kt * 64 + scol),
                     (char*)lds + base + (unsigned)li * 8192u + ldst);
    };
    auto ldaf = [&](int buf, int mi, int kk) -> bf16x8 {
        const unsigned r = (unsigned)(mi * 16 + fr);
        unsigned byt = r * 128u + (unsigned)kk * 64u + (unsigned)fq * 16u;
        byt ^= (r & 7u) << 4;
        return *(const bf16x8*)((const char*)lds +
            (unsigned)buf * 65536u + (unsigned)wr * 16384u + byt);
    };
    auto ldbf = [&](int buf, int ni, int kk) -> bf16x8 {
        const unsigned r = (unsigned)((wc & 1) * 64 + ni * 16 + fr);
        unsigned byt = r * 128u + (unsigned)kk * 64u + (unsigned)fq * 16u;
        byt ^= (r & 7u) << 4;
        return *(const bf16x8*)((const char*)lds +
            (unsigned)buf * 65536u + 32768u + (unsigned)(wc >> 1) * 16384u + byt);
    };

    const int NT = K >> 6;
    f32x4 acc[8][4] = {};

    // ---- prologue: B(0), A(0), B(1); wait so B(0)+A(0) resident -----------
    stageB(0, 0); stageB(0, 1); stageA(0, 0); stageA(0, 1);
    if (NT > 1) {
        stageB(1, 0); stageB(1, 1);
        asm volatile("s_waitcnt vmcnt(4)" ::: "memory");
    } else {
        asm volatile("s_waitcnt vmcnt(0)" ::: "memory");
    }
    __builtin_amdgcn_s_barrier();
    __builtin_amdgcn_sched_barrier(0);

    for (int t = 0; t < NT; ++t) {
        const int cur = t & 1;
        bf16x8 bfr[8];                         // B-frags, live all 4 phases
        #pragma unroll
        for (int ni = 0; ni < 4; ni++) {
            bfr[ni * 2 + 0] = ldbf(cur, ni, 0);
            bfr[ni * 2 + 1] = ldbf(cur, ni, 1);
        }
        #pragma unroll
        for (int p = 0; p < 4; p++) {
            bf16x8 a0 = ldaf(cur, 2 * p,     0);
            bf16x8 a1 = ldaf(cur, 2 * p,     1);
            bf16x8 a2 = ldaf(cur, 2 * p + 1, 0);
            bf16x8 a3 = ldaf(cur, 2 * p + 1, 1);
            if (p < 2) { if (t + 1 < NT) stageA(t + 1, p); }
            else       { if (t + 2 < NT) stageB(t + 2, p - 2); }
            if (p == 3) {                      // tile boundary: counted drain
                if (t + 2 < NT) asm volatile("s_waitcnt vmcnt(4)" ::: "memory");
                else            asm volatile("s_waitcnt vmcnt(0)" ::: "memory");
            }
            __builtin_amdgcn_s_barrier();      // pre-MFMA phase barrier
            asm volatile("s_waitcnt lgkmcnt(0)" ::: "memory");
            __builtin_amdgcn_sched_barrier(0);
            __builtin_amdgcn_s_setprio(1);
            #pragma unroll
            for (int ni = 0; ni < 4; ni++) {
                acc[2 * p][ni] = __builtin_amdgcn_mfma_f32_16x16x32_bf16(
                    a0, bfr[ni * 2 + 0], acc[2 * p][ni], 0, 0, 0);
                acc[2 * p][ni] = __builtin_amdgcn_mfma_f32_16x16x32_bf16(
                    a1, bfr[ni * 2 + 1], acc[2 * p][ni], 0, 0, 0);
                acc[2 * p + 1][ni] = __builtin_amdgcn_mfma_f32_16x16x32_bf16(
                    a2, bfr[ni * 2 + 0], acc[2 * p + 1][ni], 0, 0, 0);
                acc[2 * p + 1][ni] = __builtin_amdgcn_mfma_f32_16x16x32_bf16(
                    a3, bfr[ni * 2 + 1], acc[2 * p + 1][ni], 0, 0, 0);
            }
            __builtin_amdgcn_s_setprio(0);
            __builtin_amdgcn_sched_barrier(0);
            if (p == 3) {                      // tile-end barrier only
                __builtin_amdgcn_s_barrier();
                __builtin_amdgcn_sched_barrier(0);
            }
        }
    }

    // ---- epilogue: LDS-bounce, conflict-free read, coalesced stores --------
    const int erow = tid >> 4;                  // 0..31 (fixed per quarter-wave)
    const int echk = tid & 15;                  // 16B-chunk base within row
    #pragma unroll
    for (int h2 = 0; h2 < 2; ++h2) {
        __builtin_amdgcn_s_barrier();           // K-loop done / prev pass read
        if (wr == h2) {                         // this half's acc -> LDS fp32
            #pragma unroll
            for (int mi = 0; mi < 8; mi++) {
                #pragma unroll
                for (int ni = 0; ni < 4; ni++) {
                    const int nl = wc * 64 + ni * 16 + fr;      // block-local col
                    const float bcol = (!BROW && bias) ? bias[bn * 256 + nl] : 0.0f;
                    f32x4 brow = {0, 0, 0, 0};
                    if (BROW) brow = *(const f32x4*)(bias + bm * 256 + h2 * 128 + mi * 16 + fq * 4);
                    #pragma unroll
                    for (int r = 0; r < 4; r++) {
                        const int lm = mi * 16 + fq * 4 + r;    // 0..127
                        float v = acc[mi][ni][r] * scale + (BROW ? brow[r] : bcol);
                        if (EPI == 1) v = fmaxf(v, 0.0f);
                        const unsigned byt = ((unsigned)lm * 1024u + (unsigned)nl * 4u)
                                             ^ ((unsigned)(lm & 7) << 4);
                        *(float*)((char*)lds + byt) = v;
                    }
                }
            }
        }
        __builtin_amdgcn_s_barrier();
        #pragma unroll
        for (int j = 0; j < 16; j++) {
            const int row = erow + 32 * (j >> 2);               // 0..127
            const int c   = echk + 16 * (j & 3);                // 0..63 chunks
            const unsigned byt = ((unsigned)row * 1024u + (unsigned)c * 16u)
                                 ^ ((unsigned)(row & 7) << 4);
            f32x4 v = *(const f32x4*)((const char*)lds + byt);
            const int m = bm * 256 + h2 * 128 + row;
            const int ncol = bn * 256 + c * 4;
            const size_t offc = (size_t)bz * sC + (size_t)m * N + ncol;
            if (EPI == 2) {                     // fp16 residual RMW
                unsigned short* cp = (unsigned short*)Cv + offc;
                u16x4 hv = *(const u16x4*)cp;
                u16x4 o;
                #pragma unroll
                for (int r = 0; r < 4; r++) o[r] = f2h(h2f(hv[r]) + v[r]);
                *(u16x4*)cp = o;
            } else {
                u16x4 o;
                o[0] = f2bf(v[0]); o[1] = f2bf(v[1]); o[2] = f2bf(v[2]); o[3] = f2bf(v[3]);
                *(u16x4*)((unsigned short*)Cv + offc) = o;
            }
        }
    }
}

// ---------------- masked softmax (mask from tokens), group-local ------------
__global__ __launch_bounds__(256)
void softmax_kernel(unsigned short* __restrict__ sc, const int* __restrict__ tokg) {
    const int row = blockIdx.x * 4 + (threadIdx.x >> 6);   // row in [0, G*NS)
    const int l = threadIdx.x & 63;
    const int b = row >> 10;                               // batch local to group
    unsigned short* rp = sc + (size_t)row * NS;
    const int* trow = tokg + (size_t)b * NS;
    float v[16];
    float mx = -3.4e38f;
    #pragma unroll
    for (int j = 0; j < 2; j++) {
        u16x8 u = *(const u16x8*)(rp + j * 512 + l * 8);
        i32x4 t0 = *(const i32x4*)(trow + j * 512 + l * 8);
        i32x4 t1 = *(const i32x4*)(trow + j * 512 + l * 8 + 4);
        #pragma unroll
        for (int i = 0; i < 8; i++) {
            const int tk = (i < 4) ? t0[i] : t1[i - 4];
            const float s = (tk == 0) ? -__builtin_inff() : bf2f(u[i]);
            v[j * 8 + i] = s;
            mx = fmaxf(mx, s);
        }
    }
    #pragma unroll
    for (int off = 32; off >= 1; off >>= 1) mx = fmaxf(mx, __shfl_xor(mx, off));
    float sum = 0.f;
    #pragma unroll
    for (int i = 0; i < 16; i++) { v[i] = __expf(v[i] - mx); sum += v[i]; }
    #pragma unroll
    for (int off = 32; off >= 1; off >>= 1) sum += __shfl_xor(sum, off);
    const float inv = 1.0f / sum;
    #pragma unroll
    for (int j = 0; j < 2; j++) {
        u16x8 o;
        #pragma unroll
        for (int i = 0; i < 8; i++) o[i] = f2bf(v[j * 8 + i] * inv);
        *(u16x8*)(rp + j * 512 + l * 8) = o;
    }
}

// ---------------- pool stage 1: partial masked sums over 128-row chunks -----
__global__ __launch_bounds__(256)
void pool1_kernel(const unsigned short* __restrict__ ln,
                  const int* __restrict__ tokg,
                  float* __restrict__ part, float* __restrict__ cnts,
                  int gbase) {                     // gbase: global batch offset
    const int d = blockIdx.x * 256 + threadIdx.x;  // 0..767
    const int b = blockIdx.y;                      // local batch
    const int z = blockIdx.z;                      // seq chunk 0..7
    float s = 0.f, cnt = 0.f;
    const int i0 = z * 128;
    for (int i = i0; i < i0 + 128; i++) {
        const int tk = tokg[b * NS + i];
        if (tk != 0) { s += bf2f(ln[((size_t)b * NS + i) * ND + d]); cnt += 1.0f; }
    }
    part[((size_t)z * NB + (gbase + b)) * ND + d] = s;
    if (d == 0) cnts[z * NB + (gbase + b)] = cnt;
}

// ---------------- pool stage 2: finalize -----------------------------------
__global__ __launch_bounds__(256)
void pool2_kernel(const float* __restrict__ part, const float* __restrict__ cnts,
                  float* __restrict__ pooled) {
    const int d = blockIdx.x * 256 + threadIdx.x;
    const int b = blockIdx.y;                      // global batch
    float s = 0.f, cnt = 0.f;
    #pragma unroll
    for (int z = 0; z < 8; z++) {
        s += part[((size_t)z * NB + b) * ND + d];
        cnt += cnts[z * NB + b];
    }
    pooled[(size_t)b * ND + d] = s / fmaxf(cnt, 1.0f);
}

// ---------------- classifier -> FLOAT32 output ------------------------------
__global__ void cls_kernel(const float* __restrict__ pooled, const float* __restrict__ wc,
                           const float* __restrict__ bc, float* __restrict__ out) {
    const int b = blockIdx.x;
    const int l = threadIdx.x;                  // 64 threads
    float a[6] = {0, 0, 0, 0, 0, 0};
    for (int d = l; d < ND; d += 64) {
        const float p = pooled[b * ND + d];
        #pragma unroll
        for (int c = 0; c < 6; c++) a[c] += p * wc[d * 6 + c];
    }
    #pragma unroll
    for (int c = 0; c < 6; c++) {
        #pragma unroll
        for (int off = 32; off >= 1; off >>= 1) a[c] += __shfl_xor(a[c], off);
    }
    if (l == 0) {
        #pragma unroll
        for (int c = 0; c < 6; c++) out[b * 6 + c] = a[c] + bc[c];
    }
}

__global__ void zero_out_kernel(float* out, int nel) {
    const int i = blockIdx.x * 256 + threadIdx.x;
    if (i < nel) out[i] = 0.0f;
}

// ---------------------------------------------------------------------------
extern "C" void kernel_launch(void* const* d_in, const int* in_sizes, int n_in,
                              void* d_out, int out_size, void* d_ws, size_t ws_size,
                              hipStream_t stream) {
    const int*   tok  = (const int*)d_in[0];
    const float* emb  = (const float*)d_in[1];
    const float* pos  = (const float*)d_in[2];
    const float* ln1w = (const float*)d_in[3];
    const float* ln1b = (const float*)d_in[4];
    const float* ln2w = (const float*)d_in[5];
    const float* ln2b = (const float*)d_in[6];
    const float* wq   = (const float*)d_in[7];
    const float* bq   = (const float*)d_in[8];
    const float* wk   = (const float*)d_in[9];
    const float* bk   = (const float*)d_in[10];
    const float* wv   = (const float*)d_in[11];
    const float* bv   = (const float*)d_in[12];
    const float* w1   = (const float*)d_in[13];
    const float* b1   = (const float*)d_in[14];
    const float* w2   = (const float*)d_in[15];
    const float* b2   = (const float*)d_in[16];
    const float* lnfw = (const float*)d_in[17];
    const float* lnfb = (const float*)d_in[18];
    const float* wcw  = (const float*)d_in[19];
    const float* bcb  = (const float*)d_in[20];
    float* out = (float*)d_out;                 // FLOAT32 output (ref dtype)

    // ---- fixed workspace carve-up ----
    size_t off = 0;
    auto carve = [&](size_t bytes) -> char* {
        char* p = (char*)d_ws + off;
        off += (bytes + 255) & ~(size_t)255;
        return p;
    };
    unsigned short* x = (unsigned short*)carve((size_t)NM * ND * 2);   // fp16 residual
    unsigned short* wqkT = (unsigned short*)carve((size_t)NL * NH * ND * 2); // [l][1536][768]
    unsigned short* wvT  = (unsigned short*)carve((size_t)NL * ND * ND * 2);
    unsigned short* w1T  = (unsigned short*)carve((size_t)NL * ND * NH * 2);
    unsigned short* w2T  = (unsigned short*)carve((size_t)NL * NH * ND * 2);
    float* bqk    = (float*)carve((size_t)NL * NH * 4);
    float* part   = (float*)carve((size_t)8 * NB * ND * 4);
    float* cnts   = (float*)carve((size_t)8 * NB * 4);
    float* pooled = (float*)carve((size_t)NB * ND * 4);

    // ---- adaptive group size ----
    int G = 32;
    while (G >= 1) {
        const size_t pool = (size_t)G *
            ((size_t)NS * ND * 2      // n
           + (size_t)NS * NH * 2      // qk (aliased by h)
           + (size_t)NS * ND * 2      // vt
           + (size_t)NS * NS * 2);    // sc
        if (off + pool <= ws_size) break;
        G >>= 1;
    }
    if (G < 1) {
        zero_out_kernel<<<(out_size + 255) / 256, 256, 0, stream>>>(out, out_size);
        return;
    }
    const int MG = G * NS;                       // rows per group
    unsigned short* n  = (unsigned short*)carve((size_t)MG * ND * 2);
    unsigned short* qk = (unsigned short*)carve((size_t)MG * NH * 2);
    unsigned short* vt = (unsigned short*)carve((size_t)MG * ND * 2); // [b][768][1024]
    unsigned short* sc = (unsigned short*)carve((size_t)G * NS * NS * 2);
    unsigned short* h  = qk;                     // alias: qk dead after scores

    // ---- prepass ----
    embed_kernel<<<NM, 192, 0, stream>>>(tok, emb, pos, x);
    wt_kernel<<<dim3(12, 12, NL), 256, 0, stream>>>(wq, wqkT,            ND, ND, (size_t)NH * ND);
    wt_kernel<<<dim3(12, 12, NL), 256, 0, stream>>>(wk, wqkT + ND * ND,  ND, ND, (size_t)NH * ND);
    wt_kernel<<<dim3(12, 12, NL), 256, 0, stream>>>(wv, wvT,             ND, ND, (size_t)ND * ND);
    wt_kernel<<<dim3(24, 12, NL), 256, 0, stream>>>(w1, w1T,             ND, NH, (size_t)ND * NH);
    wt_kernel<<<dim3(12, 24, NL), 256, 0, stream>>>(w2, w2T,             NH, ND, (size_t)NH * ND);
    bcat_kernel<<<NL * NH / 256, 256, 0, stream>>>(bq, bk, bqk);

    const float iscale = 1.0f / sqrtf((float)ND);
    const int NGroups = NB / G;
    const int MT = MG / 256;                     // row tiles of the big GEMMs (=4G)
    // all grids here have nwg % 8 == 0 -> T1 swizzle everywhere
    for (int l = 0; l < NL; l++) {
        for (int g = 0; g < NGroups; g++) {
            const size_t rowoff = (size_t)g * MG;
            unsigned short* xg = x + rowoff * ND;
            ln_kernel<<<MG / 4, 256, 0, stream>>>(xg, ln1w + l * ND, ln1b + l * ND, n);
            // QK fused: qk[MG][1536] = n @ [wq|wk]^T + [bq|bk]
            gemm256_kernel<0, 0><<<dim3(6, MT, 1), 512, 0, stream>>>(
                n, wqkT + (size_t)l * NH * ND, bqk + l * NH, qk,
                NH, ND, ND, ND, 0, 0, 0, 1.0f, ((6 * MT) % 8 == 0) ? 1 : 0);
            // V^T direct: vt[b][d][s] = wvT[d][:] . n[b][s][:] + bv[d]
            gemm256_kernel<0, 1><<<dim3(4, 3, G), 512, 0, stream>>>(
                wvT + (size_t)l * ND * ND, n, bv + l * ND, vt,
                NS, ND, ND, ND, 0, (long)NS * ND, (long)ND * NS, 1.0f,
                ((12 * G) % 8 == 0) ? 1 : 0);
            // scores = q @ k^T * iscale   (q,k strided views of qk)
            gemm256_kernel<0, 0><<<dim3(4, 4, G), 512, 0, stream>>>(
                qk, qk + ND, nullptr, sc,
                NS, ND, NH, NH, (long)NS * NH, (long)NS * NH, (long)NS * NS, iscale,
                ((16 * G) % 8 == 0) ? 1 : 0);
            softmax_kernel<<<MG / 4, 256, 0, stream>>>(sc, tok + rowoff);
            // x += attn @ V   (Bt = vt)
            gemm256_kernel<2, 0><<<dim3(3, 4, G), 512, 0, stream>>>(
                sc, vt, nullptr, xg,
                ND, NS, NS, NS, (long)NS * NS, (long)ND * NS, (long)NS * ND, 1.0f,
                ((12 * G) % 8 == 0) ? 1 : 0);
            ln_kernel<<<MG / 4, 256, 0, stream>>>(xg, ln2w + l * ND, ln2b + l * ND, n);
            gemm256_kernel<1, 0><<<dim3(6, MT, 1), 512, 0, stream>>>(
                n, w1T + (size_t)l * ND * NH, b1 + l * NH, h,
                NH, ND, ND, ND, 0, 0, 0, 1.0f, ((6 * MT) % 8 == 0) ? 1 : 0);
            gemm256_kernel<2, 0><<<dim3(3, MT, 1), 512, 0, stream>>>(
                h, w2T + (size_t)l * ND * NH, b2 + l * ND, xg,
                ND, NH, NH, NH, 0, 0, 0, 1.0f, ((3 * MT) % 8 == 0) ? 1 : 0);
        }
    }
    for (int g = 0; g < NGroups; g++) {
        const size_t rowoff = (size_t)g * MG;
        ln_kernel<<<MG / 4, 256, 0, stream>>>(x + rowoff * ND, lnfw, lnfb, n);
        pool1_kernel<<<dim3(3, G, 8), 256, 0, stream>>>(n, tok + rowoff, part, cnts, g * G);
    }
    pool2_kernel<<<dim3(3, NB), 256, 0, stream>>>(part, cnts, pooled);
    cls_kernel<<<NB, 64, 0, stream>>>(pooled, wcw, bcb, out);
}

// Round 12
// 2442.367 us; speedup vs baseline: 1.0836x; 1.0218x over previous
//
#include <hip/hip_runtime.h>
#include <hip/hip_bf16.h>

// ---------------------------------------------------------------------------
// Transformer encoder fwd: B=32, S=1024, D=768, L=4, H=1536, C=6
// bf16 MFMA GEMMs. FP16 residual. Output FLOAT32.
// R12: (1) BN=192 template variant for PV/FFN2 -> grids become exact 2.0
// rounds (512 blocks) instead of 1.5-round makespan-quantized 384;
// (2) named per-op wrapper kernels for exact rocprof attribution.
// K-loop sync structure = R11 (pre-MFMA barrier per phase, boundary barrier,
// counted vmcnt, T2 swizzle, setprio).
// ---------------------------------------------------------------------------

typedef float f32x4 __attribute__((ext_vector_type(4)));
typedef unsigned short u16x4 __attribute__((ext_vector_type(4)));
typedef unsigned short u16x8 __attribute__((ext_vector_type(8)));
typedef int   i32x4 __attribute__((ext_vector_type(4)));
typedef __bf16 bf16x8 __attribute__((ext_vector_type(8)));

#define NB  32
#define NS  1024
#define ND  768
#define NH  1536
#define NL  4
#define NM  (NB * NS)   // 32768 rows total

__device__ __forceinline__ unsigned short f2bf(float f) {
    unsigned u = __builtin_bit_cast(unsigned, f);
    unsigned r = (u + 0x7FFFu + ((u >> 16) & 1u)) >> 16;   // RNE
    return (unsigned short)r;
}
__device__ __forceinline__ float bf2f(unsigned short h) {
    return __builtin_bit_cast(float, (unsigned)h << 16);
}
__device__ __forceinline__ unsigned short f2h(float f) {
    _Float16 h = (_Float16)f;
    return __builtin_bit_cast(unsigned short, h);
}
__device__ __forceinline__ float h2f(unsigned short u) {
    _Float16 h = __builtin_bit_cast(_Float16, u);
    return (float)h;
}

__device__ __forceinline__ void gl_lds16(const void* g, void* l) {
    __builtin_amdgcn_global_load_lds(
        (const __attribute__((address_space(1))) unsigned int*)g,
        (__attribute__((address_space(3))) unsigned int*)l, 16, 0, 0);
}

// ---------------- embedding -> fp16 residual --------------------------------
__global__ void embed_kernel(const int* __restrict__ tok,
                             const float* __restrict__ emb,
                             const float* __restrict__ pos,
                             unsigned short* __restrict__ x) {
    const int row = blockIdx.x;
    const int c = threadIdx.x;                 // 192 threads, 4 elems each
    const int tk = tok[row];
    const int s = row & (NS - 1);
    f32x4 e = *(const f32x4*)(emb + (size_t)tk * ND + c * 4);
    f32x4 p = *(const f32x4*)(pos + (size_t)s * ND + c * 4);
    u16x4 o;
    #pragma unroll
    for (int i = 0; i < 4; i++) o[i] = f2h(e[i] + p[i]);
    *(u16x4*)(x + (size_t)row * ND + c * 4) = o;
}

// ---------------- weight fp32 [R][C] -> bf16 transposed [C][R], z-strided ---
__global__ __launch_bounds__(256)
void wt_kernel(const float* __restrict__ in, unsigned short* __restrict__ out,
               int R, int Cc, size_t ozs) {
    __shared__ float ls[64][65];
    const int t = threadIdx.x;
    const size_t zi = (size_t)blockIdx.z * R * Cc;
    const size_t zo = (size_t)blockIdx.z * ozs;
    const int r0 = blockIdx.y * 64, c0 = blockIdx.x * 64;
    #pragma unroll
    for (int i = 0; i < 4; i++) {
        const int r = i * 16 + (t >> 4);
        const int c = (t & 15) * 4;
        f32x4 v = *(const f32x4*)(in + zi + (size_t)(r0 + r) * Cc + c0 + c);
        ls[r][c] = v[0]; ls[r][c + 1] = v[1]; ls[r][c + 2] = v[2]; ls[r][c + 3] = v[3];
    }
    __syncthreads();
    #pragma unroll
    for (int i = 0; i < 2; i++) {
        const int c = i * 32 + (t >> 3);
        const int r = (t & 7) * 8;
        u16x8 o;
        #pragma unroll
        for (int j = 0; j < 8; j++) o[j] = f2bf(ls[r + j][c]);
        *(u16x8*)(out + zo + (size_t)(c0 + c) * R + r0 + r) = o;
    }
}

// ---------------- concat bias [bq|bk] per layer -----------------------------
__global__ void bcat_kernel(const float* __restrict__ bq, const float* __restrict__ bk,
                            float* __restrict__ bqk) {
    const int i = blockIdx.x * 256 + threadIdx.x;       // NL*1536
    const int l = i / NH, j = i % NH;
    bqk[i] = (j < ND) ? bq[l * ND + j] : bk[l * ND + j - ND];
}

// ---------------- LayerNorm fp16 in -> bf16 out, one wave per row -----------
__global__ __launch_bounds__(256)
void ln_kernel(const unsigned short* __restrict__ x, const float* __restrict__ g,
               const float* __restrict__ bta, unsigned short* __restrict__ out) {
    const int row = blockIdx.x * 4 + (threadIdx.x >> 6);
    const int l = threadIdx.x & 63;
    const unsigned short* xr = x + (size_t)row * ND;
    f32x4 vv[3];
    float s = 0.f, ss = 0.f;
    #pragma unroll
    for (int j = 0; j < 3; j++) {
        u16x4 hv = *(const u16x4*)(xr + (j * 64 + l) * 4);
        #pragma unroll
        for (int i = 0; i < 4; i++) {
            vv[j][i] = h2f(hv[i]);
            s += vv[j][i]; ss += vv[j][i] * vv[j][i];
        }
    }
    #pragma unroll
    for (int off = 32; off >= 1; off >>= 1) {
        s += __shfl_xor(s, off); ss += __shfl_xor(ss, off);
    }
    const float mean = s * (1.0f / ND);
    const float var = ss * (1.0f / ND) - mean * mean;
    const float rstd = rsqrtf(var + 1e-5f);
    #pragma unroll
    for (int j = 0; j < 3; j++) {
        const int c = (j * 64 + l) * 4;
        f32x4 gv = *(const f32x4*)(g + c);
        f32x4 bv = *(const f32x4*)(bta + c);
        u16x4 o;
        #pragma unroll
        for (int i = 0; i < 4; i++) o[i] = f2bf((vv[j][i] - mean) * rstd * gv[i] + bv[i]);
        *(u16x4*)(out + (size_t)row * ND + c) = o;
    }
}

// ---------------- GEMM 256xBN, 8-phase: C = A[M,K] @ Bt[N,K]^T --------------
// 512 threads = 8 waves (2M x 4N), per-wave 128x(BN/4) out, BK=64.
// LDS: A dbuf 2x32K @0; B dbuf 2x(BN*128) @64K. Stage chunk = 8KB (64 rows).
// Per tile: A(t+1) @p0/p1 (4 insts), B(t+2) @p2/p3 (BN/64 insts);
// boundary vmcnt(BN/64). T2 both-sides XOR swizzle. R11 barrier scheme.
// EPI: 0 = scale+bias -> bf16; 1 = relu(bias+v) -> bf16; 2 = FP16 C += v
// BROW: bias indexed by output ROW m (for the V^T-producing GEMM).
template<int EPI, int BROW, int BN>
__device__ __forceinline__ void gemm_body(
        const unsigned short* __restrict__ A,
        const unsigned short* __restrict__ Bt,
        const float* __restrict__ bias,
        void* __restrict__ Cv,
        int N, int K, int lda, int ldb,
        long sA, long sB, long sC, float scale, int doswz) {
    constexpr int NI = BN / 64;                // B frags per wave / stage chunks
    constexpr unsigned BBYT = (unsigned)BN * 128u;
    __shared__ __align__(16) unsigned char lds[65536 + 2 * BN * 128];
    const int tid = threadIdx.x;
    const int wid = tid >> 6, l = tid & 63;
    const int wr = wid >> 2, wc = wid & 3;     // wave -> 2x4 grid
    const int fr = l & 15, fq = l >> 4;

    int bn = blockIdx.x, bm = blockIdx.y, bz = blockIdx.z;
    if (doswz) {                               // T1: XCD remap over full grid
        const int gx = gridDim.x, gy = gridDim.y;
        const int nwg = gx * gy * gridDim.z;
        const int flat = (bz * gy + bm) * gx + bn;
        int s = (flat & 7) * (nwg >> 3) + (flat >> 3);
        bn = s % gx; s /= gx; bm = s % gy; bz = s / gy;
    }

    const unsigned short* Ab = A + (size_t)bz * sA + (size_t)(bm * 256) * lda;
    const unsigned short* Bb = Bt + (size_t)bz * sB + (size_t)(bn * BN) * ldb;

    const int srow = tid >> 3;                           // 0..63
    const int scol = ((tid & 7) ^ (srow & 7)) * 8;       // elems (pre-swizzled)
    const unsigned ldst = (unsigned)wid * 1024u;         // wave base (bytes)

    auto stageA = [&](int kt, int h) {                   // 2 insts (128 rows)
        const unsigned base = (unsigned)(kt & 1) * 32768u + (unsigned)h * 16384u;
        #pragma unroll
        for (int li = 0; li < 2; li++)
            gl_lds16(Ab + (size_t)(h * 128 + li * 64 + srow) * lda + (kt * 64 + scol),
                     lds + base + (unsigned)li * 8192u + ldst);
    };
    auto stageB1 = [&](int kt, int li) {                 // 1 inst (64 rows)
        const unsigned base = 65536u + (unsigned)(kt & 1) * BBYT;
        gl_lds16(Bb + (size_t)(li * 64 + srow) * ldb + (kt * 64 + scol),
                 lds + base + (unsigned)li * 8192u + ldst);
    };
    auto ldaf = [&](int buf, int mi, int kk) -> bf16x8 {
        const unsigned r = (unsigned)(wr * 128 + mi * 16 + fr);
        unsigned byt = r * 128u + (unsigned)kk * 64u + (unsigned)fq * 16u;
        byt ^= (r & 7u) << 4;
        return *(const bf16x8*)(lds + (unsigned)buf * 32768u + byt);
    };
    auto ldbf = [&](int buf, int ni, int kk) -> bf16x8 {
        const unsigned r = (unsigned)(wc * (BN / 4) + ni * 16 + fr);
        unsigned byt = r * 128u + (unsigned)kk * 64u + (unsigned)fq * 16u;
        byt ^= (r & 7u) << 4;
        return *(const bf16x8*)(lds + 65536u + (unsigned)buf * BBYT + byt);
    };

    const int NT = K >> 6;
    f32x4 acc[8][NI] = {};

    // ---- prologue: B(0), A(0), B(1); wait so B(0)+A(0) resident -----------
    #pragma unroll
    for (int li = 0; li < NI; li++) stageB1(0, li);
    stageA(0, 0); stageA(0, 1);
    #pragma unroll
    for (int li = 0; li < NI; li++) stageB1(1, li);
    if constexpr (BN == 256) asm volatile("s_waitcnt vmcnt(4)" ::: "memory");
    else                     asm volatile("s_waitcnt vmcnt(3)" ::: "memory");
    __builtin_amdgcn_s_barrier();
    __builtin_amdgcn_sched_barrier(0);

    for (int t = 0; t < NT; ++t) {
        const int cur = t & 1;
        bf16x8 bfr[2 * NI];                    // B-frags, live all 4 phases
        #pragma unroll
        for (int ni = 0; ni < NI; ni++) {
            bfr[ni * 2 + 0] = ldbf(cur, ni, 0);
            bfr[ni * 2 + 1] = ldbf(cur, ni, 1);
        }
        #pragma unroll
        for (int p = 0; p < 4; p++) {
            bf16x8 a0 = ldaf(cur, 2 * p,     0);
            bf16x8 a1 = ldaf(cur, 2 * p,     1);
            bf16x8 a2 = ldaf(cur, 2 * p + 1, 0);
            bf16x8 a3 = ldaf(cur, 2 * p + 1, 1);
            if (p < 2) { if (t + 1 < NT) stageA(t + 1, p); }
            else if (p == 2) {
                if (t + 2 < NT) { stageB1(t + 2, 0); stageB1(t + 2, 1); }
            } else {
                if (t + 2 < NT) {
                    #pragma unroll
                    for (int li = 2; li < NI; li++) stageB1(t + 2, li);
                }
            }
            if (p == 3) {                      // boundary: B(t+2) insts fly
                if (t + 2 < NT) {
                    if constexpr (BN == 256) asm volatile("s_waitcnt vmcnt(4)" ::: "memory");
                    else                     asm volatile("s_waitcnt vmcnt(3)" ::: "memory");
                } else {
                    asm volatile("s_waitcnt vmcnt(0)" ::: "memory");
                }
            }
            __builtin_amdgcn_s_barrier();      // pre-MFMA phase barrier
            asm volatile("s_waitcnt lgkmcnt(0)" ::: "memory");
            __builtin_amdgcn_sched_barrier(0);
            __builtin_amdgcn_s_setprio(1);
            #pragma unroll
            for (int ni = 0; ni < NI; ni++) {
                acc[2 * p][ni] = __builtin_amdgcn_mfma_f32_16x16x32_bf16(
                    a0, bfr[ni * 2 + 0], acc[2 * p][ni], 0, 0, 0);
                acc[2 * p][ni] = __builtin_amdgcn_mfma_f32_16x16x32_bf16(
                    a1, bfr[ni * 2 + 1], acc[2 * p][ni], 0, 0, 0);
                acc[2 * p + 1][ni] = __builtin_amdgcn_mfma_f32_16x16x32_bf16(
                    a2, bfr[ni * 2 + 0], acc[2 * p + 1][ni], 0, 0, 0);
                acc[2 * p + 1][ni] = __builtin_amdgcn_mfma_f32_16x16x32_bf16(
                    a3, bfr[ni * 2 + 1], acc[2 * p + 1][ni], 0, 0, 0);
            }
            __builtin_amdgcn_s_setprio(0);
            __builtin_amdgcn_sched_barrier(0);
            if (p == 3) {                      // tile-end barrier only
                __builtin_amdgcn_s_barrier();
                __builtin_amdgcn_sched_barrier(0);
            }
        }
    }

    // ---- epilogue: LDS-bounce, conflict-free read, coalesced stores --------
    constexpr int WS = BN / 4;                  // wave col-span
    constexpr unsigned RST = (unsigned)BN * 4;  // bounce row stride (bytes)
    constexpr int CPR = BN / 64;                // 16-chunk groups per row
    const int erow = tid >> 4;                  // 0..31 (fixed per quarter-wave)
    const int echk = tid & 15;                  // 16B-chunk base within row
    #pragma unroll
    for (int h2 = 0; h2 < 2; ++h2) {
        __builtin_amdgcn_s_barrier();           // K-loop done / prev pass read
        if (wr == h2) {                         // this half's acc -> LDS fp32
            #pragma unroll
            for (int mi = 0; mi < 8; mi++) {
                #pragma unroll
                for (int ni = 0; ni < NI; ni++) {
                    const int nl = wc * WS + ni * 16 + fr;      // block-local col
                    const float bcol = (!BROW && bias) ? bias[bn * BN + nl] : 0.0f;
                    f32x4 brow = {0, 0, 0, 0};
                    if (BROW) brow = *(const f32x4*)(bias + bm * 256 + h2 * 128 + mi * 16 + fq * 4);
                    #pragma unroll
                    for (int r = 0; r < 4; r++) {
                        const int lm = mi * 16 + fq * 4 + r;    // 0..127
                        float v = acc[mi][ni][r] * scale + (BROW ? brow[r] : bcol);
                        if (EPI == 1) v = fmaxf(v, 0.0f);
                        const unsigned byt = ((unsigned)lm * RST + (unsigned)nl * 4u)
                                             ^ ((unsigned)(lm & 7) << 4);
                        *(float*)(lds + byt) = v;
                    }
                }
            }
        }
        __builtin_amdgcn_s_barrier();
        #pragma unroll
        for (int j = 0; j < 4 * CPR; j++) {
            const int row = erow + 32 * (j / CPR);              // 0..127
            const int c   = echk + 16 * (j % CPR);              // chunk idx
            const unsigned byt = ((unsigned)row * RST + (unsigned)c * 16u)
                                 ^ ((unsigned)(row & 7) << 4);
            f32x4 v = *(const f32x4*)(lds + byt);
            const int m = bm * 256 + h2 * 128 + row;
            const int ncol = bn * BN + c * 4;
            const size_t offc = (size_t)bz * sC + (size_t)m * N + ncol;
            if (EPI == 2) {                     // fp16 residual RMW
                unsigned short* cp = (unsigned short*)Cv + offc;
                u16x4 hv = *(const u16x4*)cp;
                u16x4 o;
                #pragma unroll
                for (int r = 0; r < 4; r++) o[r] = f2h(h2f(hv[r]) + v[r]);
                *(u16x4*)cp = o;
            } else {
                u16x4 o;
                o[0] = f2bf(v[0]); o[1] = f2bf(v[1]); o[2] = f2bf(v[2]); o[3] = f2bf(v[3]);
                *(u16x4*)((unsigned short*)Cv + offc) = o;
            }
        }
    }
}

#define GEMM_ARGS const unsigned short* A, const unsigned short* Bt, \
                  const float* bias, void* Cv, int N, int K, int lda, int ldb, \
                  long sA, long sB, long sC, float scale, int doswz
#define GEMM_PASS A, Bt, bias, Cv, N, K, lda, ldb, sA, sB, sC, scale, doswz

// named wrappers for exact rocprof attribution
__global__ __launch_bounds__(512, 2) void gemm_qkv_k (GEMM_ARGS) { gemm_body<0, 0, 256>(GEMM_PASS); }
__global__ __launch_bounds__(512, 2) void gemm_vt_k  (GEMM_ARGS) { gemm_body<0, 1, 256>(GEMM_PASS); }
__global__ __launch_bounds__(512, 2) void gemm_qk_k  (GEMM_ARGS) { gemm_body<0, 0, 256>(GEMM_PASS); }
__global__ __launch_bounds__(512, 2) void gemm_pv_k  (GEMM_ARGS) { gemm_body<2, 0, 192>(GEMM_PASS); }
__global__ __launch_bounds__(512, 2) void gemm_ffn1_k(GEMM_ARGS) { gemm_body<1, 0, 256>(GEMM_PASS); }
__global__ __launch_bounds__(512, 2) void gemm_ffn2_k(GEMM_ARGS) { gemm_body<2, 0, 192>(GEMM_PASS); }

// ---------------- masked softmax (mask from tokens), group-local ------------
__global__ __launch_bounds__(256)
void softmax_kernel(unsigned short* __restrict__ sc, const int* __restrict__ tokg) {
    const int row = blockIdx.x * 4 + (threadIdx.x >> 6);   // row in [0, G*NS)
    const int l = threadIdx.x & 63;
    const int b = row >> 10;                               // batch local to group
    unsigned short* rp = sc + (size_t)row * NS;
    const int* trow = tokg + (size_t)b * NS;
    float v[16];
    float mx = -3.4e38f;
    #pragma unroll
    for (int j = 0; j < 2; j++) {
        u16x8 u = *(const u16x8*)(rp + j * 512 + l * 8);
        i32x4 t0 = *(const i32x4*)(trow + j * 512 + l * 8);
        i32x4 t1 = *(const i32x4*)(trow + j * 512 + l * 8 + 4);
        #pragma unroll
        for (int i = 0; i < 8; i++) {
            const int tk = (i < 4) ? t0[i] : t1[i - 4];
            const float s = (tk == 0) ? -__builtin_inff() : bf2f(u[i]);
            v[j * 8 + i] = s;
            mx = fmaxf(mx, s);
        }
    }
    #pragma unroll
    for (int off = 32; off >= 1; off >>= 1) mx = fmaxf(mx, __shfl_xor(mx, off));
    float sum = 0.f;
    #pragma unroll
    for (int i = 0; i < 16; i++) { v[i] = __expf(v[i] - mx); sum += v[i]; }
    #pragma unroll
    for (int off = 32; off >= 1; off >>= 1) sum += __shfl_xor(sum, off);
    const float inv = 1.0f / sum;
    #pragma unroll
    for (int j = 0; j < 2; j++) {
        u16x8 o;
        #pragma unroll
        for (int i = 0; i < 8; i++) o[i] = f2bf(v[j * 8 + i] * inv);
        *(u16x8*)(rp + j * 512 + l * 8) = o;
    }
}

// ---------------- pool stage 1: partial masked sums over 128-row chunks -----
__global__ __launch_bounds__(256)
void pool1_kernel(const unsigned short* __restrict__ ln,
                  const int* __restrict__ tokg,
                  float* __restrict__ part, float* __restrict__ cnts,
                  int gbase) {                     // gbase: global batch offset
    const int d = blockIdx.x * 256 + threadIdx.x;  // 0..767
    const int b = blockIdx.y;                      // local batch
    const int z = blockIdx.z;                      // seq chunk 0..7
    float s = 0.f, cnt = 0.f;
    const int i0 = z * 128;
    for (int i = i0; i < i0 + 128; i++) {
        const int tk = tokg[b * NS + i];
        if (tk != 0) { s += bf2f(ln[((size_t)b * NS + i) * ND + d]); cnt += 1.0f; }
    }
    part[((size_t)z * NB + (gbase + b)) * ND + d] = s;
    if (d == 0) cnts[z * NB + (gbase + b)] = cnt;
}

// ---------------- pool stage 2: finalize -----------------------------------
__global__ __launch_bounds__(256)
void pool2_kernel(const float* __restrict__ part, const float* __restrict__ cnts,
                  float* __restrict__ pooled) {
    const int d = blockIdx.x * 256 + threadIdx.x;
    const int b = blockIdx.y;                      // global batch
    float s = 0.f, cnt = 0.f;
    #pragma unroll
    for (int z = 0; z < 8; z++) {
        s += part[((size_t)z * NB + b) * ND + d];
        cnt += cnts[z * NB + b];
    }
    pooled[(size_t)b * ND + d] = s / fmaxf(cnt, 1.0f);
}

// ---------------- classifier -> FLOAT32 output ------------------------------
__global__ void cls_kernel(const float* __restrict__ pooled, const float* __restrict__ wc,
                           const float* __restrict__ bc, float* __restrict__ out) {
    const int b = blockIdx.x;
    const int l = threadIdx.x;                  // 64 threads
    float a[6] = {0, 0, 0, 0, 0, 0};
    for (int d = l; d < ND; d += 64) {
        const float p = pooled[b * ND + d];
        #pragma unroll
        for (int c = 0; c < 6; c++) a[c] += p * wc[d * 6 + c];
    }
    #pragma unroll
    for (int c = 0; c < 6; c++) {
        #pragma unroll
        for (int off = 32; off >= 1; off >>= 1) a[c] += __shfl_xor(a[c], off);
    }
    if (l == 0) {
        #pragma unroll
        for (int c = 0; c < 6; c++) out[b * 6 + c] = a[c] + bc[c];
    }
}

__global__ void zero_out_kernel(float* out, int nel) {
    const int i = blockIdx.x * 256 + threadIdx.x;
    if (i < nel) out[i] = 0.0f;
}

// ---------------------------------------------------------------------------
extern "C" void kernel_launch(void* const* d_in, const int* in_sizes, int n_in,
                              void* d_out, int out_size, void* d_ws, size_t ws_size,
                              hipStream_t stream) {
    const int*   tok  = (const int*)d_in[0];
    const float* emb  = (const float*)d_in[1];
    const float* pos  = (const float*)d_in[2];
    const float* ln1w = (const float*)d_in[3];
    const float* ln1b = (const float*)d_in[4];
    const float* ln2w = (const float*)d_in[5];
    const float* ln2b = (const float*)d_in[6];
    const float* wq   = (const float*)d_in[7];
    const float* bq   = (const float*)d_in[8];
    const float* wk   = (const float*)d_in[9];
    const float* bk   = (const float*)d_in[10];
    const float* wv   = (const float*)d_in[11];
    const float* bv   = (const float*)d_in[12];
    const float* w1   = (const float*)d_in[13];
    const float* b1   = (const float*)d_in[14];
    const float* w2   = (const float*)d_in[15];
    const float* b2   = (const float*)d_in[16];
    const float* lnfw = (const float*)d_in[17];
    const float* lnfb = (const float*)d_in[18];
    const float* wcw  = (const float*)d_in[19];
    const float* bcb  = (const float*)d_in[20];
    float* out = (float*)d_out;                 // FLOAT32 output (ref dtype)

    // ---- fixed workspace carve-up ----
    size_t off = 0;
    auto carve = [&](size_t bytes) -> char* {
        char* p = (char*)d_ws + off;
        off += (bytes + 255) & ~(size_t)255;
        return p;
    };
    unsigned short* x = (unsigned short*)carve((size_t)NM * ND * 2);   // fp16 residual
    unsigned short* wqkT = (unsigned short*)carve((size_t)NL * NH * ND * 2); // [l][1536][768]
    unsigned short* wvT  = (unsigned short*)carve((size_t)NL * ND * ND * 2);
    unsigned short* w1T  = (unsigned short*)carve((size_t)NL * ND * NH * 2);
    unsigned short* w2T  = (unsigned short*)carve((size_t)NL * NH * ND * 2);
    float* bqk    = (float*)carve((size_t)NL * NH * 4);
    float* part   = (float*)carve((size_t)8 * NB * ND * 4);
    float* cnts   = (float*)carve((size_t)8 * NB * 4);
    float* pooled = (float*)carve((size_t)NB * ND * 4);

    // ---- adaptive group size ----
    int G = 32;
    while (G >= 1) {
        const size_t pool = (size_t)G *
            ((size_t)NS * ND * 2      // n
           + (size_t)NS * NH * 2      // qk (aliased by h)
           + (size_t)NS * ND * 2      // vt
           + (size_t)NS * NS * 2);    // sc
        if (off + pool <= ws_size) break;
        G >>= 1;
    }
    if (G < 1) {
        zero_out_kernel<<<(out_size + 255) / 256, 256, 0, stream>>>(out, out_size);
        return;
    }
    const int MG = G * NS;                       // rows per group
    unsigned short* n  = (unsigned short*)carve((size_t)MG * ND * 2);
    unsigned short* qk = (unsigned short*)carve((size_t)MG * NH * 2);
    unsigned short* vt = (unsigned short*)carve((size_t)MG * ND * 2); // [b][768][1024]
    unsigned short* sc = (unsigned short*)carve((size_t)G * NS * NS * 2);
    unsigned short* h  = qk;                     // alias: qk dead after scores

    // ---- prepass ----
    embed_kernel<<<NM, 192, 0, stream>>>(tok, emb, pos, x);
    wt_kernel<<<dim3(12, 12, NL), 256, 0, stream>>>(wq, wqkT,            ND, ND, (size_t)NH * ND);
    wt_kernel<<<dim3(12, 12, NL), 256, 0, stream>>>(wk, wqkT + ND * ND,  ND, ND, (size_t)NH * ND);
    wt_kernel<<<dim3(12, 12, NL), 256, 0, stream>>>(wv, wvT,             ND, ND, (size_t)ND * ND);
    wt_kernel<<<dim3(24, 12, NL), 256, 0, stream>>>(w1, w1T,             ND, NH, (size_t)ND * NH);
    wt_kernel<<<dim3(12, 24, NL), 256, 0, stream>>>(w2, w2T,             NH, ND, (size_t)NH * ND);
    bcat_kernel<<<NL * NH / 256, 256, 0, stream>>>(bq, bk, bqk);

    const float iscale = 1.0f / sqrtf((float)ND);
    const int NGroups = NB / G;
    const int MT = MG / 256;                     // 256-row tiles (=4G)
    for (int l = 0; l < NL; l++) {
        for (int g = 0; g < NGroups; g++) {
            const size_t rowoff = (size_t)g * MG;
            unsigned short* xg = x + rowoff * ND;
            ln_kernel<<<MG / 4, 256, 0, stream>>>(xg, ln1w + l * ND, ln1b + l * ND, n);
            // QK fused: qk[MG][1536] = n @ [wq|wk]^T + [bq|bk]   (6,MT)=768
            gemm_qkv_k<<<dim3(6, MT, 1), 512, 0, stream>>>(
                n, wqkT + (size_t)l * NH * ND, bqk + l * NH, qk,
                NH, ND, ND, ND, 0, 0, 0, 1.0f, ((6 * MT) % 8 == 0) ? 1 : 0);
            // V^T direct: vt[b][d][s]  (4,3,G)=384
            gemm_vt_k<<<dim3(4, 3, G), 512, 0, stream>>>(
                wvT + (size_t)l * ND * ND, n, bv + l * ND, vt,
                NS, ND, ND, ND, 0, (long)NS * ND, (long)ND * NS, 1.0f,
                ((12 * G) % 8 == 0) ? 1 : 0);
            // scores = q @ k^T * iscale   (4,4,G)=512
            gemm_qk_k<<<dim3(4, 4, G), 512, 0, stream>>>(
                qk, qk + ND, nullptr, sc,
                NS, ND, NH, NH, (long)NS * NH, (long)NS * NH, (long)NS * NS, iscale,
                ((16 * G) % 8 == 0) ? 1 : 0);
            softmax_kernel<<<MG / 4, 256, 0, stream>>>(sc, tok + rowoff);
            // x += attn @ V   (BN=192: (4,4,G)=512 = 2.0 rounds)
            gemm_pv_k<<<dim3(4, 4, G), 512, 0, stream>>>(
                sc, vt, nullptr, xg,
                ND, NS, NS, NS, (long)NS * NS, (long)ND * NS, (long)NS * ND, 1.0f,
                ((16 * G) % 8 == 0) ? 1 : 0);
            ln_kernel<<<MG / 4, 256, 0, stream>>>(xg, ln2w + l * ND, ln2b + l * ND, n);
            // FFN1 (6,MT)=768
            gemm_ffn1_k<<<dim3(6, MT, 1), 512, 0, stream>>>(
                n, w1T + (size_t)l * ND * NH, b1 + l * NH, h,
                NH, ND, ND, ND, 0, 0, 0, 1.0f, ((6 * MT) % 8 == 0) ? 1 : 0);
            // FFN2 (BN=192: (4,2MT)=1024? no -> (4,MT*2)... grid (4, 2*MT/2)) —
            // M tiles = MT*... M=MG rows/256 = MT; BN=192 -> N tiles = 4.
            gemm_ffn2_k<<<dim3(4, MT, 1), 512, 0, stream>>>(
                h, w2T + (size_t)l * ND * NH, b2 + l * ND, xg,
                ND, NH, NH, NH, 0, 0, 0, 1.0f, ((4 * MT) % 8 == 0) ? 1 : 0);
        }
    }
    for (int g = 0; g < NGroups; g++) {
        const size_t rowoff = (size_t)g * MG;
        ln_kernel<<<MG / 4, 256, 0, stream>>>(x + rowoff * ND, lnfw, lnfb, n);
        pool1_kernel<<<dim3(3, G, 8), 256, 0, stream>>>(n, tok + rowoff, part, cnts, g * G);
    }
    pool2_kernel<<<dim3(3, NB), 256, 0, stream>>>(part, cnts, pooled);
    cls_kernel<<<NB, 64, 0, stream>>>(pooled, wcw, bcb, out);
}

// Round 13
// 2371.859 us; speedup vs baseline: 1.1158x; 1.0297x over previous
//
#include <hip/hip_runtime.h>
#include <hip/hip_bf16.h>

// ---------------------------------------------------------------------------
// Transformer encoder fwd: B=32, S=1024, D=768, L=4, H=1536, C=6
// bf16 MFMA GEMMs. FP16 residual. Output FLOAT32.
// R13 = R12 with the K-loop barrier count cut 5 -> 2 per tile:
//   mid-tile barrier (before stageB(t+2); guarantees all waves' bfr reads
//   done via their p0 lgkmcnt(0)) + tile-end barrier (all ldaf(cur) reads
//   done via p3 lgkmcnt(0), before next tile's stageA overwrites cur).
// Per-phase lgkmcnt(0)+sched_barrier stay (per-wave); vmcnt(NI) boundary
// stays. Waves may skew a phase -> MFMA/ds_read cross-wave overlap.
// ---------------------------------------------------------------------------

typedef float f32x4 __attribute__((ext_vector_type(4)));
typedef unsigned short u16x4 __attribute__((ext_vector_type(4)));
typedef unsigned short u16x8 __attribute__((ext_vector_type(8)));
typedef int   i32x4 __attribute__((ext_vector_type(4)));
typedef __bf16 bf16x8 __attribute__((ext_vector_type(8)));

#define NB  32
#define NS  1024
#define ND  768
#define NH  1536
#define NL  4
#define NM  (NB * NS)   // 32768 rows total

__device__ __forceinline__ unsigned short f2bf(float f) {
    unsigned u = __builtin_bit_cast(unsigned, f);
    unsigned r = (u + 0x7FFFu + ((u >> 16) & 1u)) >> 16;   // RNE
    return (unsigned short)r;
}
__device__ __forceinline__ float bf2f(unsigned short h) {
    return __builtin_bit_cast(float, (unsigned)h << 16);
}
__device__ __forceinline__ unsigned short f2h(float f) {
    _Float16 h = (_Float16)f;
    return __builtin_bit_cast(unsigned short, h);
}
__device__ __forceinline__ float h2f(unsigned short u) {
    _Float16 h = __builtin_bit_cast(_Float16, u);
    return (float)h;
}

__device__ __forceinline__ void gl_lds16(const void* g, void* l) {
    __builtin_amdgcn_global_load_lds(
        (const __attribute__((address_space(1))) unsigned int*)g,
        (__attribute__((address_space(3))) unsigned int*)l, 16, 0, 0);
}

// ---------------- embedding -> fp16 residual --------------------------------
__global__ void embed_kernel(const int* __restrict__ tok,
                             const float* __restrict__ emb,
                             const float* __restrict__ pos,
                             unsigned short* __restrict__ x) {
    const int row = blockIdx.x;
    const int c = threadIdx.x;                 // 192 threads, 4 elems each
    const int tk = tok[row];
    const int s = row & (NS - 1);
    f32x4 e = *(const f32x4*)(emb + (size_t)tk * ND + c * 4);
    f32x4 p = *(const f32x4*)(pos + (size_t)s * ND + c * 4);
    u16x4 o;
    #pragma unroll
    for (int i = 0; i < 4; i++) o[i] = f2h(e[i] + p[i]);
    *(u16x4*)(x + (size_t)row * ND + c * 4) = o;
}

// ---------------- weight fp32 [R][C] -> bf16 transposed [C][R], z-strided ---
__global__ __launch_bounds__(256)
void wt_kernel(const float* __restrict__ in, unsigned short* __restrict__ out,
               int R, int Cc, size_t ozs) {
    __shared__ float ls[64][65];
    const int t = threadIdx.x;
    const size_t zi = (size_t)blockIdx.z * R * Cc;
    const size_t zo = (size_t)blockIdx.z * ozs;
    const int r0 = blockIdx.y * 64, c0 = blockIdx.x * 64;
    #pragma unroll
    for (int i = 0; i < 4; i++) {
        const int r = i * 16 + (t >> 4);
        const int c = (t & 15) * 4;
        f32x4 v = *(const f32x4*)(in + zi + (size_t)(r0 + r) * Cc + c0 + c);
        ls[r][c] = v[0]; ls[r][c + 1] = v[1]; ls[r][c + 2] = v[2]; ls[r][c + 3] = v[3];
    }
    __syncthreads();
    #pragma unroll
    for (int i = 0; i < 2; i++) {
        const int c = i * 32 + (t >> 3);
        const int r = (t & 7) * 8;
        u16x8 o;
        #pragma unroll
        for (int j = 0; j < 8; j++) o[j] = f2bf(ls[r + j][c]);
        *(u16x8*)(out + zo + (size_t)(c0 + c) * R + r0 + r) = o;
    }
}

// ---------------- concat bias [bq|bk] per layer -----------------------------
__global__ void bcat_kernel(const float* __restrict__ bq, const float* __restrict__ bk,
                            float* __restrict__ bqk) {
    const int i = blockIdx.x * 256 + threadIdx.x;       // NL*1536
    const int l = i / NH, j = i % NH;
    bqk[i] = (j < ND) ? bq[l * ND + j] : bk[l * ND + j - ND];
}

// ---------------- LayerNorm fp16 in -> bf16 out, one wave per row -----------
__global__ __launch_bounds__(256)
void ln_kernel(const unsigned short* __restrict__ x, const float* __restrict__ g,
               const float* __restrict__ bta, unsigned short* __restrict__ out) {
    const int row = blockIdx.x * 4 + (threadIdx.x >> 6);
    const int l = threadIdx.x & 63;
    const unsigned short* xr = x + (size_t)row * ND;
    f32x4 vv[3];
    float s = 0.f, ss = 0.f;
    #pragma unroll
    for (int j = 0; j < 3; j++) {
        u16x4 hv = *(const u16x4*)(xr + (j * 64 + l) * 4);
        #pragma unroll
        for (int i = 0; i < 4; i++) {
            vv[j][i] = h2f(hv[i]);
            s += vv[j][i]; ss += vv[j][i] * vv[j][i];
        }
    }
    #pragma unroll
    for (int off = 32; off >= 1; off >>= 1) {
        s += __shfl_xor(s, off); ss += __shfl_xor(ss, off);
    }
    const float mean = s * (1.0f / ND);
    const float var = ss * (1.0f / ND) - mean * mean;
    const float rstd = rsqrtf(var + 1e-5f);
    #pragma unroll
    for (int j = 0; j < 3; j++) {
        const int c = (j * 64 + l) * 4;
        f32x4 gv = *(const f32x4*)(g + c);
        f32x4 bv = *(const f32x4*)(bta + c);
        u16x4 o;
        #pragma unroll
        for (int i = 0; i < 4; i++) o[i] = f2bf((vv[j][i] - mean) * rstd * gv[i] + bv[i]);
        *(u16x4*)(out + (size_t)row * ND + c) = o;
    }
}

// ---------------- GEMM 256xBN, 8-phase, 2-barrier: C = A @ Bt^T --------------
// 512 threads = 8 waves (2M x 4N), per-wave 128x(BN/4) out, BK=64.
// LDS: A dbuf 2x32K @0; B dbuf 2x(BN*128) @64K. Stage chunk = 8KB (64 rows).
// Tile: A(t+1)@p0/p1, B(t+2)@p2/p3; mid-tile barrier before p2 staging;
// tile-end barrier + vmcnt(NI). T2 both-sides XOR swizzle.
// EPI: 0 = scale+bias -> bf16; 1 = relu(bias+v) -> bf16; 2 = FP16 C += v
// BROW: bias indexed by output ROW m (for the V^T-producing GEMM).
template<int EPI, int BROW, int BN>
__device__ __forceinline__ void gemm_body(
        const unsigned short* __restrict__ A,
        const unsigned short* __restrict__ Bt,
        const float* __restrict__ bias,
        void* __restrict__ Cv,
        int N, int K, int lda, int ldb,
        long sA, long sB, long sC, float scale, int doswz) {
    constexpr int NI = BN / 64;                // B frags per wave / stage chunks
    constexpr unsigned BBYT = (unsigned)BN * 128u;
    __shared__ __align__(16) unsigned char lds[65536 + 2 * BN * 128];
    const int tid = threadIdx.x;
    const int wid = tid >> 6, l = tid & 63;
    const int wr = wid >> 2, wc = wid & 3;     // wave -> 2x4 grid
    const int fr = l & 15, fq = l >> 4;

    int bn = blockIdx.x, bm = blockIdx.y, bz = blockIdx.z;
    if (doswz) {                               // T1: XCD remap over full grid
        const int gx = gridDim.x, gy = gridDim.y;
        const int nwg = gx * gy * gridDim.z;
        const int flat = (bz * gy + bm) * gx + bn;
        int s = (flat & 7) * (nwg >> 3) + (flat >> 3);
        bn = s % gx; s /= gx; bm = s % gy; bz = s / gy;
    }

    const unsigned short* Ab = A + (size_t)bz * sA + (size_t)(bm * 256) * lda;
    const unsigned short* Bb = Bt + (size_t)bz * sB + (size_t)(bn * BN) * ldb;

    const int srow = tid >> 3;                           // 0..63
    const int scol = ((tid & 7) ^ (srow & 7)) * 8;       // elems (pre-swizzled)
    const unsigned ldst = (unsigned)wid * 1024u;         // wave base (bytes)

    auto stageA = [&](int kt, int h) {                   // 2 insts (128 rows)
        const unsigned base = (unsigned)(kt & 1) * 32768u + (unsigned)h * 16384u;
        #pragma unroll
        for (int li = 0; li < 2; li++)
            gl_lds16(Ab + (size_t)(h * 128 + li * 64 + srow) * lda + (kt * 64 + scol),
                     lds + base + (unsigned)li * 8192u + ldst);
    };
    auto stageB1 = [&](int kt, int li) {                 // 1 inst (64 rows)
        const unsigned base = 65536u + (unsigned)(kt & 1) * BBYT;
        gl_lds16(Bb + (size_t)(li * 64 + srow) * ldb + (kt * 64 + scol),
                 lds + base + (unsigned)li * 8192u + ldst);
    };
    auto ldaf = [&](int buf, int mi, int kk) -> bf16x8 {
        const unsigned r = (unsigned)(wr * 128 + mi * 16 + fr);
        unsigned byt = r * 128u + (unsigned)kk * 64u + (unsigned)fq * 16u;
        byt ^= (r & 7u) << 4;
        return *(const bf16x8*)(lds + (unsigned)buf * 32768u + byt);
    };
    auto ldbf = [&](int buf, int ni, int kk) -> bf16x8 {
        const unsigned r = (unsigned)(wc * (BN / 4) + ni * 16 + fr);
        unsigned byt = r * 128u + (unsigned)kk * 64u + (unsigned)fq * 16u;
        byt ^= (r & 7u) << 4;
        return *(const bf16x8*)(lds + 65536u + (unsigned)buf * BBYT + byt);
    };

    const int NT = K >> 6;
    f32x4 acc[8][NI] = {};

    // ---- prologue: B(0), A(0), B(1); wait so B(0)+A(0) resident -----------
    #pragma unroll
    for (int li = 0; li < NI; li++) stageB1(0, li);
    stageA(0, 0); stageA(0, 1);
    #pragma unroll
    for (int li = 0; li < NI; li++) stageB1(1, li);
    if constexpr (BN == 256) asm volatile("s_waitcnt vmcnt(4)" ::: "memory");
    else                     asm volatile("s_waitcnt vmcnt(3)" ::: "memory");
    __builtin_amdgcn_s_barrier();
    __builtin_amdgcn_sched_barrier(0);

    for (int t = 0; t < NT; ++t) {
        const int cur = t & 1;
        bf16x8 bfr[2 * NI];                    // B-frags, live all 4 phases
        #pragma unroll
        for (int ni = 0; ni < NI; ni++) {
            bfr[ni * 2 + 0] = ldbf(cur, ni, 0);
            bfr[ni * 2 + 1] = ldbf(cur, ni, 1);
        }
        #pragma unroll
        for (int p = 0; p < 4; p++) {
            if (p == 2) {                      // mid-tile barrier: all waves'
                __builtin_amdgcn_s_barrier();  // bfr reads done (their p0
                __builtin_amdgcn_sched_barrier(0); // lgkmcnt(0) executed)
            }
            bf16x8 a0 = ldaf(cur, 2 * p,     0);
            bf16x8 a1 = ldaf(cur, 2 * p,     1);
            bf16x8 a2 = ldaf(cur, 2 * p + 1, 0);
            bf16x8 a3 = ldaf(cur, 2 * p + 1, 1);
            if (p < 2) { if (t + 1 < NT) stageA(t + 1, p); }
            else if (p == 2) {
                if (t + 2 < NT) { stageB1(t + 2, 0); stageB1(t + 2, 1); }
            } else {
                if (t + 2 < NT) {
                    #pragma unroll
                    for (int li = 2; li < NI; li++) stageB1(t + 2, li);
                }
            }
            if (p == 3) {                      // boundary: B(t+2) insts fly
                if (t + 2 < NT) {
                    if constexpr (BN == 256) asm volatile("s_waitcnt vmcnt(4)" ::: "memory");
                    else                     asm volatile("s_waitcnt vmcnt(3)" ::: "memory");
                } else {
                    asm volatile("s_waitcnt vmcnt(0)" ::: "memory");
                }
            }
            asm volatile("s_waitcnt lgkmcnt(0)" ::: "memory");
            __builtin_amdgcn_sched_barrier(0);
            __builtin_amdgcn_s_setprio(1);
            #pragma unroll
            for (int ni = 0; ni < NI; ni++) {
                acc[2 * p][ni] = __builtin_amdgcn_mfma_f32_16x16x32_bf16(
                    a0, bfr[ni * 2 + 0], acc[2 * p][ni], 0, 0, 0);
                acc[2 * p][ni] = __builtin_amdgcn_mfma_f32_16x16x32_bf16(
                    a1, bfr[ni * 2 + 1], acc[2 * p][ni], 0, 0, 0);
                acc[2 * p + 1][ni] = __builtin_amdgcn_mfma_f32_16x16x32_bf16(
                    a2, bfr[ni * 2 + 0], acc[2 * p + 1][ni], 0, 0, 0);
                acc[2 * p + 1][ni] = __builtin_amdgcn_mfma_f32_16x16x32_bf16(
                    a3, bfr[ni * 2 + 1], acc[2 * p + 1][ni], 0, 0, 0);
            }
            __builtin_amdgcn_s_setprio(0);
            __builtin_amdgcn_sched_barrier(0);
            if (p == 3) {                      // tile-end barrier: all waves'
                __builtin_amdgcn_s_barrier();  // ldaf(cur) reads done (p3
                __builtin_amdgcn_sched_barrier(0); // lgkmcnt(0) executed)
            }
        }
    }

    // ---- epilogue: LDS-bounce, conflict-free read, coalesced stores --------
    constexpr int WS = BN / 4;                  // wave col-span
    constexpr unsigned RST = (unsigned)BN * 4;  // bounce row stride (bytes)
    constexpr int CPR = BN / 64;                // 16-chunk groups per row
    const int erow = tid >> 4;                  // 0..31 (fixed per quarter-wave)
    const int echk = tid & 15;                  // 16B-chunk base within row
    #pragma unroll
    for (int h2 = 0; h2 < 2; ++h2) {
        __builtin_amdgcn_s_barrier();           // K-loop done / prev pass read
        if (wr == h2) {                         // this half's acc -> LDS fp32
            #pragma unroll
            for (int mi = 0; mi < 8; mi++) {
                #pragma unroll
                for (int ni = 0; ni < NI; ni++) {
                    const int nl = wc * WS + ni * 16 + fr;      // block-local col
                    const float bcol = (!BROW && bias) ? bias[bn * BN + nl] : 0.0f;
                    f32x4 brow = {0, 0, 0, 0};
                    if (BROW) brow = *(const f32x4*)(bias + bm * 256 + h2 * 128 + mi * 16 + fq * 4);
                    #pragma unroll
                    for (int r = 0; r < 4; r++) {
                        const int lm = mi * 16 + fq * 4 + r;    // 0..127
                        float v = acc[mi][ni][r] * scale + (BROW ? brow[r] : bcol);
                        if (EPI == 1) v = fmaxf(v, 0.0f);
                        const unsigned byt = ((unsigned)lm * RST + (unsigned)nl * 4u)
                                             ^ ((unsigned)(lm & 7) << 4);
                        *(float*)(lds + byt) = v;
                    }
                }
            }
        }
        __builtin_amdgcn_s_barrier();
        #pragma unroll
        for (int j = 0; j < 4 * CPR; j++) {
            const int row = erow + 32 * (j / CPR);              // 0..127
            const int c   = echk + 16 * (j % CPR);              // chunk idx
            const unsigned byt = ((unsigned)row * RST + (unsigned)c * 16u)
                                 ^ ((unsigned)(row & 7) << 4);
            f32x4 v = *(const f32x4*)(lds + byt);
            const int m = bm * 256 + h2 * 128 + row;
            const int ncol = bn * BN + c * 4;
            const size_t offc = (size_t)bz * sC + (size_t)m * N + ncol;
            if (EPI == 2) {                     // fp16 residual RMW
                unsigned short* cp = (unsigned short*)Cv + offc;
                u16x4 hv = *(const u16x4*)cp;
                u16x4 o;
                #pragma unroll
                for (int r = 0; r < 4; r++) o[r] = f2h(h2f(hv[r]) + v[r]);
                *(u16x4*)cp = o;
            } else {
                u16x4 o;
                o[0] = f2bf(v[0]); o[1] = f2bf(v[1]); o[2] = f2bf(v[2]); o[3] = f2bf(v[3]);
                *(u16x4*)((unsigned short*)Cv + offc) = o;
            }
        }
    }
}

#define GEMM_ARGS const unsigned short* A, const unsigned short* Bt, \
                  const float* bias, void* Cv, int N, int K, int lda, int ldb, \
                  long sA, long sB, long sC, float scale, int doswz
#define GEMM_PASS A, Bt, bias, Cv, N, K, lda, ldb, sA, sB, sC, scale, doswz

// named wrappers for exact rocprof attribution
__global__ __launch_bounds__(512, 2) void gemm_qkv_k (GEMM_ARGS) { gemm_body<0, 0, 256>(GEMM_PASS); }
__global__ __launch_bounds__(512, 2) void gemm_vt_k  (GEMM_ARGS) { gemm_body<0, 1, 256>(GEMM_PASS); }
__global__ __launch_bounds__(512, 2) void gemm_qk_k  (GEMM_ARGS) { gemm_body<0, 0, 256>(GEMM_PASS); }
__global__ __launch_bounds__(512, 2) void gemm_pv_k  (GEMM_ARGS) { gemm_body<2, 0, 192>(GEMM_PASS); }
__global__ __launch_bounds__(512, 2) void gemm_ffn1_k(GEMM_ARGS) { gemm_body<1, 0, 256>(GEMM_PASS); }
__global__ __launch_bounds__(512, 2) void gemm_ffn2_k(GEMM_ARGS) { gemm_body<2, 0, 192>(GEMM_PASS); }

// ---------------- masked softmax (mask from tokens), group-local ------------
__global__ __launch_bounds__(256)
void softmax_kernel(unsigned short* __restrict__ sc, const int* __restrict__ tokg) {
    const int row = blockIdx.x * 4 + (threadIdx.x >> 6);   // row in [0, G*NS)
    const int l = threadIdx.x & 63;
    const int b = row >> 10;                               // batch local to group
    unsigned short* rp = sc + (size_t)row * NS;
    const int* trow = tokg + (size_t)b * NS;
    float v[16];
    float mx = -3.4e38f;
    #pragma unroll
    for (int j = 0; j < 2; j++) {
        u16x8 u = *(const u16x8*)(rp + j * 512 + l * 8);
        i32x4 t0 = *(const i32x4*)(trow + j * 512 + l * 8);
        i32x4 t1 = *(const i32x4*)(trow + j * 512 + l * 8 + 4);
        #pragma unroll
        for (int i = 0; i < 8; i++) {
            const int tk = (i < 4) ? t0[i] : t1[i - 4];
            const float s = (tk == 0) ? -__builtin_inff() : bf2f(u[i]);
            v[j * 8 + i] = s;
            mx = fmaxf(mx, s);
        }
    }
    #pragma unroll
    for (int off = 32; off >= 1; off >>= 1) mx = fmaxf(mx, __shfl_xor(mx, off));
    float sum = 0.f;
    #pragma unroll
    for (int i = 0; i < 16; i++) { v[i] = __expf(v[i] - mx); sum += v[i]; }
    #pragma unroll
    for (int off = 32; off >= 1; off >>= 1) sum += __shfl_xor(sum, off);
    const float inv = 1.0f / sum;
    #pragma unroll
    for (int j = 0; j < 2; j++) {
        u16x8 o;
        #pragma unroll
        for (int i = 0; i < 8; i++) o[i] = f2bf(v[j * 8 + i] * inv);
        *(u16x8*)(rp + j * 512 + l * 8) = o;
    }
}

// ---------------- pool stage 1: partial masked sums over 128-row chunks -----
__global__ __launch_bounds__(256)
void pool1_kernel(const unsigned short* __restrict__ ln,
                  const int* __restrict__ tokg,
                  float* __restrict__ part, float* __restrict__ cnts,
                  int gbase) {                     // gbase: global batch offset
    const int d = blockIdx.x * 256 + threadIdx.x;  // 0..767
    const int b = blockIdx.y;                      // local batch
    const int z = blockIdx.z;                      // seq chunk 0..7
    float s = 0.f, cnt = 0.f;
    const int i0 = z * 128;
    for (int i = i0; i < i0 + 128; i++) {
        const int tk = tokg[b * NS + i];
        if (tk != 0) { s += bf2f(ln[((size_t)b * NS + i) * ND + d]); cnt += 1.0f; }
    }
    part[((size_t)z * NB + (gbase + b)) * ND + d] = s;
    if (d == 0) cnts[z * NB + (gbase + b)] = cnt;
}

// ---------------- pool stage 2: finalize -----------------------------------
__global__ __launch_bounds__(256)
void pool2_kernel(const float* __restrict__ part, const float* __restrict__ cnts,
                  float* __restrict__ pooled) {
    const int d = blockIdx.x * 256 + threadIdx.x;
    const int b = blockIdx.y;                      // global batch
    float s = 0.f, cnt = 0.f;
    #pragma unroll
    for (int z = 0; z < 8; z++) {
        s += part[((size_t)z * NB + b) * ND + d];
        cnt += cnts[z * NB + b];
    }
    pooled[(size_t)b * ND + d] = s / fmaxf(cnt, 1.0f);
}

// ---------------- classifier -> FLOAT32 output ------------------------------
__global__ void cls_kernel(const float* __restrict__ pooled, const float* __restrict__ wc,
                           const float* __restrict__ bc, float* __restrict__ out) {
    const int b = blockIdx.x;
    const int l = threadIdx.x;                  // 64 threads
    float a[6] = {0, 0, 0, 0, 0, 0};
    for (int d = l; d < ND; d += 64) {
        const float p = pooled[b * ND + d];
        #pragma unroll
        for (int c = 0; c < 6; c++) a[c] += p * wc[d * 6 + c];
    }
    #pragma unroll
    for (int c = 0; c < 6; c++) {
        #pragma unroll
        for (int off = 32; off >= 1; off >>= 1) a[c] += __shfl_xor(a[c], off);
    }
    if (l == 0) {
        #pragma unroll
        for (int c = 0; c < 6; c++) out[b * 6 + c] = a[c] + bc[c];
    }
}

__global__ void zero_out_kernel(float* out, int nel) {
    const int i = blockIdx.x * 256 + threadIdx.x;
    if (i < nel) out[i] = 0.0f;
}

// ---------------------------------------------------------------------------
extern "C" void kernel_launch(void* const* d_in, const int* in_sizes, int n_in,
                              void* d_out, int out_size, void* d_ws, size_t ws_size,
                              hipStream_t stream) {
    const int*   tok  = (const int*)d_in[0];
    const float* emb  = (const float*)d_in[1];
    const float* pos  = (const float*)d_in[2];
    const float* ln1w = (const float*)d_in[3];
    const float* ln1b = (const float*)d_in[4];
    const float* ln2w = (const float*)d_in[5];
    const float* ln2b = (const float*)d_in[6];
    const float* wq   = (const float*)d_in[7];
    const float* bq   = (const float*)d_in[8];
    const float* wk   = (const float*)d_in[9];
    const float* bk   = (const float*)d_in[10];
    const float* wv   = (const float*)d_in[11];
    const float* bv   = (const float*)d_in[12];
    const float* w1   = (const float*)d_in[13];
    const float* b1   = (const float*)d_in[14];
    const float* w2   = (const float*)d_in[15];
    const float* b2   = (const float*)d_in[16];
    const float* lnfw = (const float*)d_in[17];
    const float* lnfb = (const float*)d_in[18];
    const float* wcw  = (const float*)d_in[19];
    const float* bcb  = (const float*)d_in[20];
    float* out = (float*)d_out;                 // FLOAT32 output (ref dtype)

    // ---- fixed workspace carve-up ----
    size_t off = 0;
    auto carve = [&](size_t bytes) -> char* {
        char* p = (char*)d_ws + off;
        off += (bytes + 255) & ~(size_t)255;
        return p;
    };
    unsigned short* x = (unsigned short*)carve((size_t)NM * ND * 2);   // fp16 residual
    unsigned short* wqkT = (unsigned short*)carve((size_t)NL * NH * ND * 2); // [l][1536][768]
    unsigned short* wvT  = (unsigned short*)carve((size_t)NL * ND * ND * 2);
    unsigned short* w1T  = (unsigned short*)carve((size_t)NL * ND * NH * 2);
    unsigned short* w2T  = (unsigned short*)carve((size_t)NL * NH * ND * 2);
    float* bqk    = (float*)carve((size_t)NL * NH * 4);
    float* part   = (float*)carve((size_t)8 * NB * ND * 4);
    float* cnts   = (float*)carve((size_t)8 * NB * 4);
    float* pooled = (float*)carve((size_t)NB * ND * 4);

    // ---- adaptive group size ----
    int G = 32;
    while (G >= 1) {
        const size_t pool = (size_t)G *
            ((size_t)NS * ND * 2      // n
           + (size_t)NS * NH * 2      // qk (aliased by h)
           + (size_t)NS * ND * 2      // vt
           + (size_t)NS * NS * 2);    // sc
        if (off + pool <= ws_size) break;
        G >>= 1;
    }
    if (G < 1) {
        zero_out_kernel<<<(out_size + 255) / 256, 256, 0, stream>>>(out, out_size);
        return;
    }
    const int MG = G * NS;                       // rows per group
    unsigned short* n  = (unsigned short*)carve((size_t)MG * ND * 2);
    unsigned short* qk = (unsigned short*)carve((size_t)MG * NH * 2);
    unsigned short* vt = (unsigned short*)carve((size_t)MG * ND * 2); // [b][768][1024]
    unsigned short* sc = (unsigned short*)carve((size_t)G * NS * NS * 2);
    unsigned short* h  = qk;                     // alias: qk dead after scores

    // ---- prepass ----
    embed_kernel<<<NM, 192, 0, stream>>>(tok, emb, pos, x);
    wt_kernel<<<dim3(12, 12, NL), 256, 0, stream>>>(wq, wqkT,            ND, ND, (size_t)NH * ND);
    wt_kernel<<<dim3(12, 12, NL), 256, 0, stream>>>(wk, wqkT + ND * ND,  ND, ND, (size_t)NH * ND);
    wt_kernel<<<dim3(12, 12, NL), 256, 0, stream>>>(wv, wvT,             ND, ND, (size_t)ND * ND);
    wt_kernel<<<dim3(24, 12, NL), 256, 0, stream>>>(w1, w1T,             ND, NH, (size_t)ND * NH);
    wt_kernel<<<dim3(12, 24, NL), 256, 0, stream>>>(w2, w2T,             NH, ND, (size_t)NH * ND);
    bcat_kernel<<<NL * NH / 256, 256, 0, stream>>>(bq, bk, bqk);

    const float iscale = 1.0f / sqrtf((float)ND);
    const int NGroups = NB / G;
    const int MT = MG / 256;                     // 256-row tiles (=4G)
    for (int l = 0; l < NL; l++) {
        for (int g = 0; g < NGroups; g++) {
            const size_t rowoff = (size_t)g * MG;
            unsigned short* xg = x + rowoff * ND;
            ln_kernel<<<MG / 4, 256, 0, stream>>>(xg, ln1w + l * ND, ln1b + l * ND, n);
            // QK fused: qk[MG][1536] = n @ [wq|wk]^T + [bq|bk]   (6,MT)=768
            gemm_qkv_k<<<dim3(6, MT, 1), 512, 0, stream>>>(
                n, wqkT + (size_t)l * NH * ND, bqk + l * NH, qk,
                NH, ND, ND, ND, 0, 0, 0, 1.0f, ((6 * MT) % 8 == 0) ? 1 : 0);
            // V^T direct: vt[b][d][s]  (4,3,G)=384
            gemm_vt_k<<<dim3(4, 3, G), 512, 0, stream>>>(
                wvT + (size_t)l * ND * ND, n, bv + l * ND, vt,
                NS, ND, ND, ND, 0, (long)NS * ND, (long)ND * NS, 1.0f,
                ((12 * G) % 8 == 0) ? 1 : 0);
            // scores = q @ k^T * iscale   (4,4,G)=512
            gemm_qk_k<<<dim3(4, 4, G), 512, 0, stream>>>(
                qk, qk + ND, nullptr, sc,
                NS, ND, NH, NH, (long)NS * NH, (long)NS * NH, (long)NS * NS, iscale,
                ((16 * G) % 8 == 0) ? 1 : 0);
            softmax_kernel<<<MG / 4, 256, 0, stream>>>(sc, tok + rowoff);
            // x += attn @ V   (BN=192: (4,4,G)=512 = 2.0 rounds)
            gemm_pv_k<<<dim3(4, 4, G), 512, 0, stream>>>(
                sc, vt, nullptr, xg,
                ND, NS, NS, NS, (long)NS * NS, (long)ND * NS, (long)NS * ND, 1.0f,
                ((16 * G) % 8 == 0) ? 1 : 0);
            ln_kernel<<<MG / 4, 256, 0, stream>>>(xg, ln2w + l * ND, ln2b + l * ND, n);
            // FFN1 (6,MT)=768
            gemm_ffn1_k<<<dim3(6, MT, 1), 512, 0, stream>>>(
                n, w1T + (size_t)l * ND * NH, b1 + l * NH, h,
                NH, ND, ND, ND, 0, 0, 0, 1.0f, ((6 * MT) % 8 == 0) ? 1 : 0);
            // FFN2 (BN=192: (4,MT)=512 = 2.0 rounds)
            gemm_ffn2_k<<<dim3(4, MT, 1), 512, 0, stream>>>(
                h, w2T + (size_t)l * ND * NH, b2 + l * ND, xg,
                ND, NH, NH, NH, 0, 0, 0, 1.0f, ((4 * MT) % 8 == 0) ? 1 : 0);
        }
    }
    for (int g = 0; g < NGroups; g++) {
        const size_t rowoff = (size_t)g * MG;
        ln_kernel<<<MG / 4, 256, 0, stream>>>(x + rowoff * ND, lnfw, lnfb, n);
        pool1_kernel<<<dim3(3, G, 8), 256, 0, stream>>>(n, tok + rowoff, part, cnts, g * G);
    }
    pool2_kernel<<<dim3(3, NB), 256, 0, stream>>>(part, cnts, pooled);
    cls_kernel<<<NB, 64, 0, stream>>>(pooled, wcw, bcb, out);
}